// Round 3
// baseline (2005.289 us; speedup 1.0000x reference)
//
#include <hip/hip_runtime.h>
#include <math.h>

#define NNODES 50000
#define DIM 128
#define DEDGE 64

typedef __attribute__((ext_vector_type(8))) short bf16x8;
typedef __attribute__((ext_vector_type(4))) float f32x4;
typedef __attribute__((ext_vector_type(2))) float f32x2;

// ---------------------------------------------------------------------------
// packed f32x2 atomic add (global_atomic_pk_add_f32) with safe fallback
// ---------------------------------------------------------------------------
__device__ __forceinline__ void atomic_add2(float* p, float a, float b) {
#if __has_builtin(__builtin_amdgcn_global_atomic_fadd_v2f32)
    typedef __attribute__((address_space(1))) f32x2 gf2;
    __builtin_amdgcn_global_atomic_fadd_v2f32((gf2*)(unsigned long long)p, (f32x2){a, b});
#else
    unsafeAtomicAdd(p, a);
    unsafeAtomicAdd(p + 1, b);
#endif
}

__device__ __forceinline__ float bf_lo(unsigned u) { return __builtin_bit_cast(float, u << 16); }
__device__ __forceinline__ float bf_hi(unsigned u) { return __builtin_bit_cast(float, u & 0xFFFF0000u); }
__device__ __forceinline__ float bf_s(short s) {
    return __builtin_bit_cast(float, ((unsigned)(unsigned short)s) << 16);
}
__device__ __forceinline__ unsigned short f2b_rtn(float f) {
    unsigned u = __builtin_bit_cast(unsigned, f);
    u += 0x7FFFu + ((u >> 16) & 1u);
    return (unsigned short)(u >> 16);
}

// ---------------------------------------------------------------------------
// edge_index dtype detection (int64 per reference vs int32 per harness doc)
// ---------------------------------------------------------------------------
__global__ void detect_mode_kernel(const void* __restrict__ ei, int* __restrict__ flag) {
    __shared__ int bad;
    if (threadIdx.x == 0) bad = 0;
    __syncthreads();
    const long long* p = (const long long*)ei;
    int localbad = 0;
    for (int i = threadIdx.x; i < 4096; i += blockDim.x) {
        long long v = p[i];
        if (v < 0 || v >= NNODES) localbad = 1;
    }
    if (localbad) atomicOr(&bad, 1);
    __syncthreads();
    if (threadIdx.x == 0) *flag = bad ? 0 : 1;   // 1 = int64 mode
}

__device__ __forceinline__ int load_idx(const void* ei, long long pos, int mode64) {
    if (mode64) return (int)((const long long*)ei)[pos];
    return ((const int*)ei)[pos];
}

// ---------------------------------------------------------------------------
// split f32 -> bf16 hi (RTZ) + bf16 lo (RTN of remainder); hi+lo ~ 2^-17 rel
// ---------------------------------------------------------------------------
__device__ __forceinline__ void split_bf16(float f, short& hi, short& lo) {
    union { float f; unsigned u; } v; v.f = f;
    unsigned uh = v.u & 0xFFFF0000u;
    hi = (short)(uh >> 16);
    union { unsigned u; float f; } hh; hh.u = uh;
    float r = f - hh.f;
    union { float f; unsigned u; } w; w.f = r;
    unsigned t = w.u + 0x7FFFu + ((w.u >> 16) & 1u);
    lo = (short)(t >> 16);
}

// ---------------------------------------------------------------------------
// prep: transpose weights to WT[col][k], split to hi/lo bf16, into ws.
// ---------------------------------------------------------------------------
__global__ void prep_weights(const float* __restrict__ aW0, const float* __restrict__ aW1,
                             const float* __restrict__ mW0, const float* __restrict__ mW1,
                             const float* __restrict__ lpW1, short* __restrict__ wt)
{
    int i = blockIdx.x * 256 + threadIdx.x;   // 0..98303 (384 blocks)
    const float* src; int K, hioff, looff, j;
    if (i < 8192)        { src = aW0;  K = 64;  hioff = 0;      looff = 8192;   j = i; }
    else if (i < 16384)  { src = aW1;  K = 64;  hioff = 16384;  looff = 24576;  j = i - 8192; }
    else if (i < 49152)  { src = mW0;  K = 256; hioff = 32768;  looff = 65536;  j = i - 16384; }
    else if (i < 81920)  { src = mW1;  K = 256; hioff = 98304;  looff = 131072; j = i - 49152; }
    else                 { src = lpW1; K = 128; hioff = 163840; looff = 180224; j = i - 81920; }
    int col = j / K, k = j % K;
    float f = src[k * DIM + col];
    short hi, lo; split_bf16(f, hi, lo);
    wt[hioff + col * K + k] = hi;
    wt[looff + col * K + k] = lo;
}

// f32 -> bf16 table conversion (coalesced, 8 elems/thread)
__global__ void f32_to_bf16_kernel(const float* __restrict__ in,
                                   unsigned short* __restrict__ out, long long n)
{
    long long i = ((long long)blockIdx.x * 256 + threadIdx.x) * 8;
    if (i >= n) return;
    f32x4 a = *(const f32x4*)(in + i);
    f32x4 b = *(const f32x4*)(in + i + 4);
    unsigned short v[8];
#pragma unroll
    for (int t = 0; t < 4; t++) { v[t] = f2b_rtn(a[t]); v[4 + t] = f2b_rtn(b[t]); }
    unsigned p0 = v[0] | ((unsigned)v[1] << 16);
    unsigned p1 = v[2] | ((unsigned)v[3] << 16);
    unsigned p2 = v[4] | ((unsigned)v[5] << 16);
    unsigned p3 = v[6] | ((unsigned)v[7] << 16);
    f32x4 pk = {__builtin_bit_cast(float, p0), __builtin_bit_cast(float, p1),
                __builtin_bit_cast(float, p2), __builtin_bit_cast(float, p3)};
    *(f32x4*)(out + i) = pk;
}

// ---------------------------------------------------------------------------
// edge message + scatter: agg[dst] += relu(h[src] + eattr @ W + b)
// wave-per-16-edges MFMA; staged in LDS; epilogue: lane owns cols {2l,2l+1},
// gathers bf16 pair of h[src], does one packed f32x2 atomic per row.
// ---------------------------------------------------------------------------
__global__ __launch_bounds__(256, 4) void edge_msg_mfma(
    const unsigned short* __restrict__ hb, const void* __restrict__ ei,
    const int* __restrict__ modep, const float* __restrict__ eattr,
    const short* __restrict__ Whi, const short* __restrict__ Wlo,
    const float* __restrict__ bvec, float* __restrict__ agg, int E)
{
    __shared__ float e_lds[4][16][132];
    const int mode64 = *modep;
    const int lane = threadIdx.x & 63;
    const int w = threadIdx.x >> 6;
    const int lg = lane >> 4, lr = lane & 15;
    const long long e0 = ((long long)blockIdx.x * 4 + w) * 16;
    if (e0 >= E) return;

    const long long erow = (e0 + lr < E) ? (e0 + lr) : (E - 1);
    int sidx = load_idx(ei, erow, mode64);
    int didx = load_idx(ei, (long long)E + erow, mode64);

    f32x4 acc[8];
#pragma unroll
    for (int n = 0; n < 8; n++) {
        float b = bvec[n * 16 + lr];
        acc[n] = (f32x4){b, b, b, b};
    }
    bf16x8 ahi[2], alo[2];
#pragma unroll
    for (int kc = 0; kc < 2; kc++) {
        const float* p = eattr + erow * DEDGE + kc * 32 + lg * 8;
        f32x4 v0 = *(const f32x4*)p;
        f32x4 v1 = *(const f32x4*)(p + 4);
#pragma unroll
        for (int i = 0; i < 4; i++) {
            short h, l;
            split_bf16(v0[i], h, l); ahi[kc][i] = h; alo[kc][i] = l;
            split_bf16(v1[i], h, l); ahi[kc][4 + i] = h; alo[kc][4 + i] = l;
        }
    }

#pragma unroll
    for (int n = 0; n < 8; n++) {
#pragma unroll
        for (int kc = 0; kc < 2; kc++) {
            const int off = (n * 16 + lr) * DEDGE + kc * 32 + lg * 8;
            bf16x8 bh = *(const bf16x8*)(Whi + off);
            bf16x8 bl = *(const bf16x8*)(Wlo + off);
            acc[n] = __builtin_amdgcn_mfma_f32_16x16x32_bf16(ahi[kc], bh, acc[n], 0, 0, 0);
            acc[n] = __builtin_amdgcn_mfma_f32_16x16x32_bf16(alo[kc], bh, acc[n], 0, 0, 0);
            acc[n] = __builtin_amdgcn_mfma_f32_16x16x32_bf16(ahi[kc], bl, acc[n], 0, 0, 0);
        }
    }
    // D layout: col = n*16+lr, row = lg*4+r
#pragma unroll
    for (int n = 0; n < 8; n++)
#pragma unroll
        for (int r = 0; r < 4; r++)
            e_lds[w][lg * 4 + r][n * 16 + lr] = acc[n][r];

    for (int r = 0; r < 16; r++) {
        long long e = e0 + r;
        if (e >= E) break;
        int si = __shfl(sidx, r);
        int di = __shfl(didx, r);
        f32x2 ev = *(const f32x2*)&e_lds[w][r][2 * lane];
        unsigned u = *(const unsigned*)&hb[(long long)si * DIM + 2 * lane];
        float m0 = fmaxf(ev.x + bf_lo(u), 0.f);
        float m1 = fmaxf(ev.y + bf_hi(u), 0.f);
        atomic_add2(&agg[(long long)di * DIM + 2 * lane], m0, m1);
    }
}

// ---------------------------------------------------------------------------
// GIN update: hout = act([agg | (1+eps)*h] @ W(256x128) + b), wave-per-16-nodes
// optionally writes f32 and/or bf16 (LDS-staged, coalesced) copies.
// ---------------------------------------------------------------------------
__global__ __launch_bounds__(256, 4) void node_update_mfma(
    const float* __restrict__ agg, const float* __restrict__ h,
    const short* __restrict__ Whi, const short* __restrict__ Wlo,
    const float* __restrict__ bvec, const float* __restrict__ epsp,
    float* __restrict__ houtf, unsigned short* __restrict__ houtb, int relu_flag)
{
    __shared__ float st[4][16][132];
    const int lane = threadIdx.x & 63;
    const int w = threadIdx.x >> 6;
    const int lg = lane >> 4, lr = lane & 15;
    const int n0 = (blockIdx.x * 4 + w) * 16;
    if (n0 >= NNODES) return;
    const float s = 1.0f + epsp[0];
    const int arow = (n0 + lr < NNODES) ? (n0 + lr) : (NNODES - 1);

    f32x4 acc[8];
#pragma unroll
    for (int n = 0; n < 8; n++) {
        float b = bvec[n * 16 + lr];
        acc[n] = (f32x4){b, b, b, b};
    }
#pragma unroll
    for (int kc = 0; kc < 8; kc++) {
        const int k = kc * 32 + lg * 8;
        float buf[8];
        if (k < 128) {
            f32x4 v0 = *(const f32x4*)(agg + (long long)arow * DIM + k);
            f32x4 v1 = *(const f32x4*)(agg + (long long)arow * DIM + k + 4);
#pragma unroll
            for (int i = 0; i < 4; i++) { buf[i] = v0[i]; buf[4 + i] = v1[i]; }
        } else {
            f32x4 v0 = *(const f32x4*)(h + (long long)arow * DIM + (k - 128));
            f32x4 v1 = *(const f32x4*)(h + (long long)arow * DIM + (k - 128) + 4);
#pragma unroll
            for (int i = 0; i < 4; i++) { buf[i] = s * v0[i]; buf[4 + i] = s * v1[i]; }
        }
        bf16x8 ahi, alo;
#pragma unroll
        for (int i = 0; i < 8; i++) { short hh, ll; split_bf16(buf[i], hh, ll); ahi[i] = hh; alo[i] = ll; }
#pragma unroll
        for (int n = 0; n < 8; n++) {
            const int off = (n * 16 + lr) * 256 + k;
            bf16x8 bh = *(const bf16x8*)(Whi + off);
            bf16x8 bl = *(const bf16x8*)(Wlo + off);
            acc[n] = __builtin_amdgcn_mfma_f32_16x16x32_bf16(ahi, bh, acc[n], 0, 0, 0);
            acc[n] = __builtin_amdgcn_mfma_f32_16x16x32_bf16(alo, bh, acc[n], 0, 0, 0);
            acc[n] = __builtin_amdgcn_mfma_f32_16x16x32_bf16(ahi, bl, acc[n], 0, 0, 0);
        }
    }
#pragma unroll
    for (int n = 0; n < 8; n++) {
#pragma unroll
        for (int r = 0; r < 4; r++) {
            float z = acc[n][r];
            z = relu_flag ? fmaxf(z, 0.f) : (z > 0.f ? z : 0.2f * z);
            int row = n0 + lg * 4 + r;
            if (houtf && row < NNODES)
                houtf[(long long)row * DIM + n * 16 + lr] = z;
            st[w][lg * 4 + r][n * 16 + lr] = z;
        }
    }
    if (houtb) {
        for (int r = 0; r < 16; r++) {
            int row = n0 + r;
            if (row >= NNODES) break;
            f32x2 v = *(const f32x2*)&st[w][r][2 * lane];
            unsigned pk = (unsigned)f2b_rtn(v.x) | ((unsigned)f2b_rtn(v.y) << 16);
            *(unsigned*)&houtb[(long long)row * DIM + 2 * lane] = pk;
        }
    }
}

// ---------------------------------------------------------------------------
// edge head: he = h[src]*h[dst] from bf16 table (exact f32 product), write f32;
// z = leaky(he@W1+b1); logits = z@W2+b2; yhat = softmax2.
// ---------------------------------------------------------------------------
__global__ __launch_bounds__(256, 6) void edge_head_mfma(
    const unsigned short* __restrict__ hb, const void* __restrict__ ei,
    const int* __restrict__ modep,
    const short* __restrict__ W1hi, const short* __restrict__ W1lo,
    const float* __restrict__ b1, const float* __restrict__ W2,
    const float* __restrict__ b2,
    float* __restrict__ out_he, float* __restrict__ out_y, int E)
{
    const int mode64 = *modep;
    const int lane = threadIdx.x & 63;
    const int w = threadIdx.x >> 6;
    const int lg = lane >> 4, lr = lane & 15;
    const long long e0 = ((long long)blockIdx.x * 4 + w) * 16;
    if (e0 >= E) return;
    const long long erow = (e0 + lr < E) ? (e0 + lr) : (E - 1);
    int si = load_idx(ei, erow, mode64);
    int di = load_idx(ei, (long long)E + erow, mode64);

    f32x4 acc[8];
#pragma unroll
    for (int n = 0; n < 8; n++) {
        float b = b1[n * 16 + lr];
        acc[n] = (f32x4){b, b, b, b};
    }
    bf16x8 ahi[4], alo[4];
#pragma unroll
    for (int kc = 0; kc < 4; kc++) {
        const int k = kc * 32 + lg * 8;
        bf16x8 hs = *(const bf16x8*)(hb + (long long)si * DIM + k);
        bf16x8 hd = *(const bf16x8*)(hb + (long long)di * DIM + k);
        f32x4 p0, p1;
#pragma unroll
        for (int i = 0; i < 4; i++) {
            p0[i] = bf_s(hs[i]) * bf_s(hd[i]);
            p1[i] = bf_s(hs[4 + i]) * bf_s(hd[4 + i]);
        }
        if (e0 + lr < E) {
            *(f32x4*)(out_he + erow * DIM + k) = p0;
            *(f32x4*)(out_he + erow * DIM + k + 4) = p1;
        }
#pragma unroll
        for (int i = 0; i < 4; i++) {
            short hh, ll;
            split_bf16(p0[i], hh, ll); ahi[kc][i] = hh; alo[kc][i] = ll;
            split_bf16(p1[i], hh, ll); ahi[kc][4 + i] = hh; alo[kc][4 + i] = ll;
        }
    }
#pragma unroll
    for (int n = 0; n < 8; n++) {
#pragma unroll
        for (int kc = 0; kc < 4; kc++) {
            const int off = (n * 16 + lr) * 128 + kc * 32 + lg * 8;
            bf16x8 bh = *(const bf16x8*)(W1hi + off);
            bf16x8 bl = *(const bf16x8*)(W1lo + off);
            acc[n] = __builtin_amdgcn_mfma_f32_16x16x32_bf16(ahi[kc], bh, acc[n], 0, 0, 0);
            acc[n] = __builtin_amdgcn_mfma_f32_16x16x32_bf16(alo[kc], bh, acc[n], 0, 0, 0);
            acc[n] = __builtin_amdgcn_mfma_f32_16x16x32_bf16(ahi[kc], bl, acc[n], 0, 0, 0);
        }
    }
    // logits: leaky(z) dotted with W2 cols, reduce over the 16 cols (lr)
    float q0[4] = {0.f, 0.f, 0.f, 0.f}, q1[4] = {0.f, 0.f, 0.f, 0.f};
#pragma unroll
    for (int n = 0; n < 8; n++) {
        float w2a = W2[(n * 16 + lr) * 2 + 0];
        float w2b = W2[(n * 16 + lr) * 2 + 1];
#pragma unroll
        for (int r = 0; r < 4; r++) {
            float z = acc[n][r];
            z = z > 0.f ? z : 0.2f * z;
            q0[r] = fmaf(z, w2a, q0[r]);
            q1[r] = fmaf(z, w2b, q1[r]);
        }
    }
#pragma unroll
    for (int m = 1; m < 16; m <<= 1) {
#pragma unroll
        for (int r = 0; r < 4; r++) {
            q0[r] += __shfl_xor(q0[r], m);
            q1[r] += __shfl_xor(q1[r], m);
        }
    }
    if (lr == 0) {
        float c0 = b2[0], c1 = b2[1];
#pragma unroll
        for (int r = 0; r < 4; r++) {
            long long e = e0 + lg * 4 + r;
            if (e < E) {
                float l0 = q0[r] + c0, l1 = q1[r] + c1;
                float mx = fmaxf(l0, l1);
                float x0 = expf(l0 - mx), x1 = expf(l1 - mx);
                float inv = 1.f / (x0 + x1);
                out_y[e * 2 + 0] = x0 * inv;
                out_y[e * 2 + 1] = x1 * inv;
            }
        }
    }
}

extern "C" void kernel_launch(void* const* d_in, const int* in_sizes, int n_in,
                              void* d_out, int out_size, void* d_ws, size_t ws_size,
                              hipStream_t stream)
{
    const float* x     = (const float*)d_in[0];
    const void*  ei    = d_in[1];
    const float* eattr = (const float*)d_in[2];
    const float* aW0   = (const float*)d_in[3];
    const float* ab0   = (const float*)d_in[4];
    const float* mW0   = (const float*)d_in[5];
    const float* mb0   = (const float*)d_in[6];
    const float* eps0  = (const float*)d_in[7];
    const float* aW1   = (const float*)d_in[8];
    const float* ab1   = (const float*)d_in[9];
    const float* mW1   = (const float*)d_in[10];
    const float* mb1   = (const float*)d_in[11];
    const float* eps1  = (const float*)d_in[12];
    const float* lpW1  = (const float*)d_in[13];
    const float* lpb1  = (const float*)d_in[14];
    const float* lpW2  = (const float*)d_in[15];
    const float* lpb2  = (const float*)d_in[16];

    const int E = in_sizes[1] / 2;
    const long long NTAB = (long long)NNODES * DIM;   // 6.4M

    float* wsf  = (float*)d_ws;
    int*   flag = (int*)d_ws;
    float* agg  = wsf + 64;
    float* h1   = agg + NTAB;
    short* wt   = (short*)(h1 + NTAB);
    unsigned short* xb_h2b = (unsigned short*)(wt + 196608); // x bf16, later h2 bf16
    unsigned short* h1b    = xb_h2b + NTAB;

    float* out_he = (float*)d_out;
    float* out_y  = out_he + (long long)E * DIM;

    const short* aW0hi = wt,           *aW0lo = wt + 8192;
    const short* aW1hi = wt + 16384,   *aW1lo = wt + 24576;
    const short* mW0hi = wt + 32768,   *mW0lo = wt + 65536;
    const short* mW1hi = wt + 98304,   *mW1lo = wt + 131072;
    const short* lpW1hi = wt + 163840, *lpW1lo = wt + 180224;

    detect_mode_kernel<<<1, 256, 0, stream>>>(ei, flag);
    prep_weights<<<384, 256, 0, stream>>>(aW0, aW1, mW0, mW1, lpW1, wt);
    f32_to_bf16_kernel<<<(int)(NTAB / 8 / 256), 256, 0, stream>>>(x, xb_h2b, NTAB);

    const int eblocks = (E + 63) / 64;
    const int nblocks = (NNODES + 63) / 64;

    // ---- layer 0 ----
    hipMemsetAsync(agg, 0, NTAB * sizeof(float), stream);
    edge_msg_mfma<<<eblocks, 256, 0, stream>>>(xb_h2b, ei, flag, eattr, aW0hi, aW0lo, ab0, agg, E);
    node_update_mfma<<<nblocks, 256, 0, stream>>>(agg, x, mW0hi, mW0lo, mb0, eps0, h1, h1b, 0);

    // ---- layer 1 ----
    hipMemsetAsync(agg, 0, NTAB * sizeof(float), stream);
    edge_msg_mfma<<<eblocks, 256, 0, stream>>>(h1b, ei, flag, eattr, aW1hi, aW1lo, ab1, agg, E);
    node_update_mfma<<<nblocks, 256, 0, stream>>>(agg, h1, mW1hi, mW1lo, mb1, eps1, nullptr, xb_h2b, 1);

    // ---- link predictor head ----
    edge_head_mfma<<<eblocks, 256, 0, stream>>>(xb_h2b, ei, flag, lpW1hi, lpW1lo, lpb1, lpW2, lpb2,
                                                out_he, out_y, E);
}

// Round 4
// 1335.518 us; speedup vs baseline: 1.5015x; 1.5015x over previous
//
#include <hip/hip_runtime.h>
#include <math.h>

#define NNODES 50000
#define DIM 128
#define DEDGE 64

typedef __attribute__((ext_vector_type(8))) short bf16x8;
typedef __attribute__((ext_vector_type(4))) float f32x4;
typedef __attribute__((ext_vector_type(2))) float f32x2;

__device__ __forceinline__ float bf_lo(unsigned u) { return __builtin_bit_cast(float, u << 16); }
__device__ __forceinline__ float bf_hi(unsigned u) { return __builtin_bit_cast(float, u & 0xFFFF0000u); }
__device__ __forceinline__ float bf_s(short s) {
    return __builtin_bit_cast(float, ((unsigned)(unsigned short)s) << 16);
}
__device__ __forceinline__ unsigned short f2b_rtn(float f) {
    unsigned u = __builtin_bit_cast(unsigned, f);
    u += 0x7FFFu + ((u >> 16) & 1u);
    return (unsigned short)(u >> 16);
}

// ---------------------------------------------------------------------------
// edge_index dtype detection (int64 per reference vs int32 per harness doc)
// ---------------------------------------------------------------------------
__global__ void detect_mode_kernel(const void* __restrict__ ei, int* __restrict__ flag) {
    __shared__ int bad;
    if (threadIdx.x == 0) bad = 0;
    __syncthreads();
    const long long* p = (const long long*)ei;
    int localbad = 0;
    for (int i = threadIdx.x; i < 4096; i += blockDim.x) {
        long long v = p[i];
        if (v < 0 || v >= NNODES) localbad = 1;
    }
    if (localbad) atomicOr(&bad, 1);
    __syncthreads();
    if (threadIdx.x == 0) *flag = bad ? 0 : 1;   // 1 = int64 mode
}

__device__ __forceinline__ int load_idx(const void* ei, long long pos, int mode64) {
    if (mode64) return (int)((const long long*)ei)[pos];
    return ((const int*)ei)[pos];
}

// ---------------------------------------------------------------------------
// split f32 -> bf16 hi (RTZ) + bf16 lo (RTN of remainder); hi+lo ~ 2^-17 rel
// ---------------------------------------------------------------------------
__device__ __forceinline__ void split_bf16(float f, short& hi, short& lo) {
    union { float f; unsigned u; } v; v.f = f;
    unsigned uh = v.u & 0xFFFF0000u;
    hi = (short)(uh >> 16);
    union { unsigned u; float f; } hh; hh.u = uh;
    float r = f - hh.f;
    union { float f; unsigned u; } w; w.f = r;
    unsigned t = w.u + 0x7FFFu + ((w.u >> 16) & 1u);
    lo = (short)(t >> 16);
}

// ---------------------------------------------------------------------------
// prep: transpose weights to WT[col][k], split to hi/lo bf16, into ws.
// ---------------------------------------------------------------------------
__global__ void prep_weights(const float* __restrict__ aW0, const float* __restrict__ aW1,
                             const float* __restrict__ mW0, const float* __restrict__ mW1,
                             const float* __restrict__ lpW1, short* __restrict__ wt)
{
    int i = blockIdx.x * 256 + threadIdx.x;   // 0..98303 (384 blocks)
    const float* src; int K, hioff, looff, j;
    if (i < 8192)        { src = aW0;  K = 64;  hioff = 0;      looff = 8192;   j = i; }
    else if (i < 16384)  { src = aW1;  K = 64;  hioff = 16384;  looff = 24576;  j = i - 8192; }
    else if (i < 49152)  { src = mW0;  K = 256; hioff = 32768;  looff = 65536;  j = i - 16384; }
    else if (i < 81920)  { src = mW1;  K = 256; hioff = 98304;  looff = 131072; j = i - 49152; }
    else                 { src = lpW1; K = 128; hioff = 163840; looff = 180224; j = i - 81920; }
    int col = j / K, k = j % K;
    float f = src[k * DIM + col];
    short hi, lo; split_bf16(f, hi, lo);
    wt[hioff + col * K + k] = hi;
    wt[looff + col * K + k] = lo;
}

// f32 -> bf16 table conversion (coalesced, 8 elems/thread)
__global__ void f32_to_bf16_kernel(const float* __restrict__ in,
                                   unsigned short* __restrict__ out, long long n)
{
    long long i = ((long long)blockIdx.x * 256 + threadIdx.x) * 8;
    if (i >= n) return;
    f32x4 a = *(const f32x4*)(in + i);
    f32x4 b = *(const f32x4*)(in + i + 4);
    unsigned short v[8];
#pragma unroll
    for (int t = 0; t < 4; t++) { v[t] = f2b_rtn(a[t]); v[4 + t] = f2b_rtn(b[t]); }
    unsigned p0 = v[0] | ((unsigned)v[1] << 16);
    unsigned p1 = v[2] | ((unsigned)v[3] << 16);
    unsigned p2 = v[4] | ((unsigned)v[5] << 16);
    unsigned p3 = v[6] | ((unsigned)v[7] << 16);
    f32x4 pk = {__builtin_bit_cast(float, p0), __builtin_bit_cast(float, p1),
                __builtin_bit_cast(float, p2), __builtin_bit_cast(float, p3)};
    *(f32x4*)(out + i) = pk;
}

// ---------------------------------------------------------------------------
// CSR build: histogram of dst, exclusive scan, scatter to sorted order
// ---------------------------------------------------------------------------
__global__ void hist_kernel(const void* __restrict__ ei, const int* __restrict__ modep,
                            int* __restrict__ counts, int E)
{
    const int mode64 = *modep;
    for (int e = blockIdx.x * 256 + threadIdx.x; e < E; e += gridDim.x * 256)
        atomicAdd(&counts[load_idx(ei, (long long)E + e, mode64)], 1);
}

__global__ __launch_bounds__(1024) void scan_kernel(const int* __restrict__ counts,
                                                    int* __restrict__ cursor)
{
    __shared__ int part[1024];
    const int t = threadIdx.x;
    const int CH = (NNODES + 1023) / 1024;
    const int lo = t * CH, hi = min(lo + CH, NNODES);
    int s = 0;
    for (int i = lo; i < hi; i++) s += counts[i];
    part[t] = s;
    __syncthreads();
    for (int d = 1; d < 1024; d <<= 1) {
        int v = (t >= d) ? part[t - d] : 0;
        __syncthreads();
        part[t] += v;
        __syncthreads();
    }
    int run = (t == 0) ? 0 : part[t - 1];
    for (int i = lo; i < hi; i++) { cursor[i] = run; run += counts[i]; }
}

__global__ void scatter_kernel(const void* __restrict__ ei, const int* __restrict__ modep,
                               int* __restrict__ cursor, int* __restrict__ perm,
                               int* __restrict__ srcs, int* __restrict__ dsts, int E)
{
    const int mode64 = *modep;
    for (int e = blockIdx.x * 256 + threadIdx.x; e < E; e += gridDim.x * 256) {
        int d = load_idx(ei, (long long)E + e, mode64);
        int s = load_idx(ei, e, mode64);
        int pos = atomicAdd(&cursor[d], 1);
        perm[pos] = e;
        srcs[pos] = s;
        dsts[pos] = d;
    }
}

// ---------------------------------------------------------------------------
// edge message + scatter over dst-SORTED edges:
//   agg[dst] += relu(h[src] + eattr@W + b)
// wave-per-16-sorted-edges MFMA; segmented epilogue: runs of equal dst
// accumulate in registers, one scalar-atomic burst per run boundary.
// ---------------------------------------------------------------------------
__global__ __launch_bounds__(256, 4) void edge_msg_sorted(
    const unsigned short* __restrict__ hb, const float* __restrict__ eattr,
    const int* __restrict__ perm, const int* __restrict__ srcs,
    const int* __restrict__ dsts,
    const short* __restrict__ Whi, const short* __restrict__ Wlo,
    const float* __restrict__ bvec, float* __restrict__ agg, int E)
{
    __shared__ float e_lds[4][16][132];
    const int lane = threadIdx.x & 63;
    const int w = threadIdx.x >> 6;
    const int lg = lane >> 4, lr = lane & 15;
    const long long p0 = ((long long)blockIdx.x * 4 + w) * 16;
    if (p0 >= E) return;

    const long long pos = (p0 + lr < E) ? (p0 + lr) : (E - 1);
    const int eid  = perm[pos];
    const int sidx = srcs[pos];
    const int didx = dsts[pos];

    f32x4 acc[8];
#pragma unroll
    for (int n = 0; n < 8; n++) {
        float b = bvec[n * 16 + lr];
        acc[n] = (f32x4){b, b, b, b};
    }
    bf16x8 ahi[2], alo[2];
#pragma unroll
    for (int kc = 0; kc < 2; kc++) {
        const float* p = eattr + (long long)eid * DEDGE + kc * 32 + lg * 8;
        f32x4 v0 = *(const f32x4*)p;
        f32x4 v1 = *(const f32x4*)(p + 4);
#pragma unroll
        for (int i = 0; i < 4; i++) {
            short h, l;
            split_bf16(v0[i], h, l); ahi[kc][i] = h; alo[kc][i] = l;
            split_bf16(v1[i], h, l); ahi[kc][4 + i] = h; alo[kc][4 + i] = l;
        }
    }

#pragma unroll
    for (int n = 0; n < 8; n++) {
#pragma unroll
        for (int kc = 0; kc < 2; kc++) {
            const int off = (n * 16 + lr) * DEDGE + kc * 32 + lg * 8;
            bf16x8 bh = *(const bf16x8*)(Whi + off);
            bf16x8 bl = *(const bf16x8*)(Wlo + off);
            acc[n] = __builtin_amdgcn_mfma_f32_16x16x32_bf16(ahi[kc], bh, acc[n], 0, 0, 0);
            acc[n] = __builtin_amdgcn_mfma_f32_16x16x32_bf16(alo[kc], bh, acc[n], 0, 0, 0);
            acc[n] = __builtin_amdgcn_mfma_f32_16x16x32_bf16(ahi[kc], bl, acc[n], 0, 0, 0);
        }
    }
    // D layout: col = n*16+lr, row = lg*4+r
#pragma unroll
    for (int n = 0; n < 8; n++)
#pragma unroll
        for (int r = 0; r < 4; r++)
            e_lds[w][lg * 4 + r][n * 16 + lr] = acc[n][r];

    // segmented epilogue: lane owns cols {2l,2l+1}
    float a0 = 0.f, a1 = 0.f;
    int prev = -1;
    for (int r = 0; r < 16; r++) {
        if (p0 + r >= E) break;
        int di = __shfl(didx, r);
        int si = __shfl(sidx, r);
        f32x2 ev = *(const f32x2*)&e_lds[w][r][2 * lane];
        unsigned u = *(const unsigned*)&hb[(long long)si * DIM + 2 * lane];
        float m0 = fmaxf(ev.x + bf_lo(u), 0.f);
        float m1 = fmaxf(ev.y + bf_hi(u), 0.f);
        if (di != prev && prev >= 0) {
            float* d = &agg[(long long)prev * DIM + 2 * lane];
            unsafeAtomicAdd(d, a0);
            unsafeAtomicAdd(d + 1, a1);
            a0 = 0.f; a1 = 0.f;
        }
        a0 += m0; a1 += m1; prev = di;
    }
    if (prev >= 0) {
        float* d = &agg[(long long)prev * DIM + 2 * lane];
        unsafeAtomicAdd(d, a0);
        unsafeAtomicAdd(d + 1, a1);
    }
}

// ---------------------------------------------------------------------------
// GIN update: hout = act([agg | (1+eps)*h] @ W(256x128) + b), wave-per-16-nodes
// optionally writes f32 and/or bf16 (LDS-staged, coalesced) copies.
// ---------------------------------------------------------------------------
__global__ __launch_bounds__(256, 4) void node_update_mfma(
    const float* __restrict__ agg, const float* __restrict__ h,
    const short* __restrict__ Whi, const short* __restrict__ Wlo,
    const float* __restrict__ bvec, const float* __restrict__ epsp,
    float* __restrict__ houtf, unsigned short* __restrict__ houtb, int relu_flag)
{
    __shared__ float st[4][16][132];
    const int lane = threadIdx.x & 63;
    const int w = threadIdx.x >> 6;
    const int lg = lane >> 4, lr = lane & 15;
    const int n0 = (blockIdx.x * 4 + w) * 16;
    if (n0 >= NNODES) return;
    const float s = 1.0f + epsp[0];
    const int arow = (n0 + lr < NNODES) ? (n0 + lr) : (NNODES - 1);

    f32x4 acc[8];
#pragma unroll
    for (int n = 0; n < 8; n++) {
        float b = bvec[n * 16 + lr];
        acc[n] = (f32x4){b, b, b, b};
    }
#pragma unroll
    for (int kc = 0; kc < 8; kc++) {
        const int k = kc * 32 + lg * 8;
        float buf[8];
        if (k < 128) {
            f32x4 v0 = *(const f32x4*)(agg + (long long)arow * DIM + k);
            f32x4 v1 = *(const f32x4*)(agg + (long long)arow * DIM + k + 4);
#pragma unroll
            for (int i = 0; i < 4; i++) { buf[i] = v0[i]; buf[4 + i] = v1[i]; }
        } else {
            f32x4 v0 = *(const f32x4*)(h + (long long)arow * DIM + (k - 128));
            f32x4 v1 = *(const f32x4*)(h + (long long)arow * DIM + (k - 128) + 4);
#pragma unroll
            for (int i = 0; i < 4; i++) { buf[i] = s * v0[i]; buf[4 + i] = s * v1[i]; }
        }
        bf16x8 ahi, alo;
#pragma unroll
        for (int i = 0; i < 8; i++) { short hh, ll; split_bf16(buf[i], hh, ll); ahi[i] = hh; alo[i] = ll; }
#pragma unroll
        for (int n = 0; n < 8; n++) {
            const int off = (n * 16 + lr) * 256 + k;
            bf16x8 bh = *(const bf16x8*)(Whi + off);
            bf16x8 bl = *(const bf16x8*)(Wlo + off);
            acc[n] = __builtin_amdgcn_mfma_f32_16x16x32_bf16(ahi, bh, acc[n], 0, 0, 0);
            acc[n] = __builtin_amdgcn_mfma_f32_16x16x32_bf16(alo, bh, acc[n], 0, 0, 0);
            acc[n] = __builtin_amdgcn_mfma_f32_16x16x32_bf16(ahi, bl, acc[n], 0, 0, 0);
        }
    }
#pragma unroll
    for (int n = 0; n < 8; n++) {
#pragma unroll
        for (int r = 0; r < 4; r++) {
            float z = acc[n][r];
            z = relu_flag ? fmaxf(z, 0.f) : (z > 0.f ? z : 0.2f * z);
            int row = n0 + lg * 4 + r;
            if (houtf && row < NNODES)
                houtf[(long long)row * DIM + n * 16 + lr] = z;
            st[w][lg * 4 + r][n * 16 + lr] = z;
        }
    }
    if (houtb) {
        for (int r = 0; r < 16; r++) {
            int row = n0 + r;
            if (row >= NNODES) break;
            f32x2 v = *(const f32x2*)&st[w][r][2 * lane];
            unsigned pk = (unsigned)f2b_rtn(v.x) | ((unsigned)f2b_rtn(v.y) << 16);
            *(unsigned*)&houtb[(long long)row * DIM + 2 * lane] = pk;
        }
    }
}

// ---------------------------------------------------------------------------
// edge head: he = h[src]*h[dst] from bf16 table (exact f32 product), write f32;
// z = leaky(he@W1+b1); logits = z@W2+b2; yhat = softmax2.
// 512-thread persistent blocks; W1 hi/lo staged in LDS in fragment order
// (chunk id c = n*4+kc, offset c*64+lane 16B-units) -> conflict-free ds_read.
// ---------------------------------------------------------------------------
__global__ __launch_bounds__(512) void edge_head_mfma(
    const unsigned short* __restrict__ hb, const void* __restrict__ ei,
    const int* __restrict__ modep,
    const short* __restrict__ W1hi, const short* __restrict__ W1lo,
    const float* __restrict__ b1, const float* __restrict__ W2,
    const float* __restrict__ b2,
    float* __restrict__ out_he, float* __restrict__ out_y, int E)
{
    __shared__ short WHs[16384];   // 32 KB
    __shared__ short WLs[16384];   // 32 KB
    const int lane = threadIdx.x & 63;
    const int w = threadIdx.x >> 6;
    const int lg = lane >> 4, lr = lane & 15;

    for (int cc = threadIdx.x; cc < 2048; cc += 512) {
        int c = cc >> 6, ln = cc & 63;
        int col = (c >> 2) * 16 + (ln & 15);
        int k = (c & 3) * 32 + (ln >> 4) * 8;
        *(bf16x8*)&WHs[cc * 8] = *(const bf16x8*)(W1hi + col * 128 + k);
        *(bf16x8*)&WLs[cc * 8] = *(const bf16x8*)(W1lo + col * 128 + k);
    }
    __syncthreads();

    const int mode64 = *modep;
    const int nt = (E + 15) >> 4;

    for (int tile = blockIdx.x * 8 + w; tile < nt; tile += gridDim.x * 8) {
        const long long e0 = (long long)tile * 16;
        const long long erow = (e0 + lr < E) ? (e0 + lr) : (E - 1);
        int si = load_idx(ei, erow, mode64);
        int di = load_idx(ei, (long long)E + erow, mode64);

        f32x4 acc[8];
#pragma unroll
        for (int n = 0; n < 8; n++) {
            float b = b1[n * 16 + lr];
            acc[n] = (f32x4){b, b, b, b};
        }
        bf16x8 ahi[4], alo[4];
#pragma unroll
        for (int kc = 0; kc < 4; kc++) {
            const int k = kc * 32 + lg * 8;
            bf16x8 hs = *(const bf16x8*)(hb + (long long)si * DIM + k);
            bf16x8 hd = *(const bf16x8*)(hb + (long long)di * DIM + k);
            f32x4 p0, p1;
#pragma unroll
            for (int i = 0; i < 4; i++) {
                p0[i] = bf_s(hs[i]) * bf_s(hd[i]);
                p1[i] = bf_s(hs[4 + i]) * bf_s(hd[4 + i]);
            }
            if (e0 + lr < E) {
                *(f32x4*)(out_he + erow * DIM + k) = p0;
                *(f32x4*)(out_he + erow * DIM + k + 4) = p1;
            }
#pragma unroll
            for (int i = 0; i < 4; i++) {
                short hh, ll;
                split_bf16(p0[i], hh, ll); ahi[kc][i] = hh; alo[kc][i] = ll;
                split_bf16(p1[i], hh, ll); ahi[kc][4 + i] = hh; alo[kc][4 + i] = ll;
            }
        }
#pragma unroll
        for (int n = 0; n < 8; n++) {
#pragma unroll
            for (int kc = 0; kc < 4; kc++) {
                const int cc = ((n * 4 + kc) * 64 + lane) * 8;
                bf16x8 bh = *(const bf16x8*)&WHs[cc];
                bf16x8 bl = *(const bf16x8*)&WLs[cc];
                acc[n] = __builtin_amdgcn_mfma_f32_16x16x32_bf16(ahi[kc], bh, acc[n], 0, 0, 0);
                acc[n] = __builtin_amdgcn_mfma_f32_16x16x32_bf16(alo[kc], bh, acc[n], 0, 0, 0);
                acc[n] = __builtin_amdgcn_mfma_f32_16x16x32_bf16(ahi[kc], bl, acc[n], 0, 0, 0);
            }
        }
        // logits: leaky(z) dotted with W2 cols, reduce over the 16 cols (lr)
        float q0[4] = {0.f, 0.f, 0.f, 0.f}, q1[4] = {0.f, 0.f, 0.f, 0.f};
#pragma unroll
        for (int n = 0; n < 8; n++) {
            float w2a = W2[(n * 16 + lr) * 2 + 0];
            float w2b = W2[(n * 16 + lr) * 2 + 1];
#pragma unroll
            for (int r = 0; r < 4; r++) {
                float z = acc[n][r];
                z = z > 0.f ? z : 0.2f * z;
                q0[r] = fmaf(z, w2a, q0[r]);
                q1[r] = fmaf(z, w2b, q1[r]);
            }
        }
#pragma unroll
        for (int m = 1; m < 16; m <<= 1) {
#pragma unroll
            for (int r = 0; r < 4; r++) {
                q0[r] += __shfl_xor(q0[r], m);
                q1[r] += __shfl_xor(q1[r], m);
            }
        }
        if (lr == 0) {
            float c0 = b2[0], c1 = b2[1];
#pragma unroll
            for (int r = 0; r < 4; r++) {
                long long e = e0 + lg * 4 + r;
                if (e < E) {
                    float l0 = q0[r] + c0, l1 = q1[r] + c1;
                    float mx = fmaxf(l0, l1);
                    float x0 = expf(l0 - mx), x1 = expf(l1 - mx);
                    float inv = 1.f / (x0 + x1);
                    out_y[e * 2 + 0] = x0 * inv;
                    out_y[e * 2 + 1] = x1 * inv;
                }
            }
        }
    }
}

extern "C" void kernel_launch(void* const* d_in, const int* in_sizes, int n_in,
                              void* d_out, int out_size, void* d_ws, size_t ws_size,
                              hipStream_t stream)
{
    const float* x     = (const float*)d_in[0];
    const void*  ei    = d_in[1];
    const float* eattr = (const float*)d_in[2];
    const float* aW0   = (const float*)d_in[3];
    const float* ab0   = (const float*)d_in[4];
    const float* mW0   = (const float*)d_in[5];
    const float* mb0   = (const float*)d_in[6];
    const float* eps0  = (const float*)d_in[7];
    const float* aW1   = (const float*)d_in[8];
    const float* ab1   = (const float*)d_in[9];
    const float* mW1   = (const float*)d_in[10];
    const float* mb1   = (const float*)d_in[11];
    const float* eps1  = (const float*)d_in[12];
    const float* lpW1  = (const float*)d_in[13];
    const float* lpb1  = (const float*)d_in[14];
    const float* lpW2  = (const float*)d_in[15];
    const float* lpb2  = (const float*)d_in[16];

    const int E = in_sizes[1] / 2;
    const long long NTAB = (long long)NNODES * DIM;   // 6.4M

    float* wsf  = (float*)d_ws;
    int*   flag = (int*)d_ws;
    float* agg  = wsf + 64;
    float* h1   = agg + NTAB;
    short* wt   = (short*)(h1 + NTAB);
    unsigned short* xb_h2b = (unsigned short*)(wt + 196608); // x bf16, later h2 bf16
    unsigned short* h1b    = xb_h2b + NTAB;
    int* counts = (int*)(h1b + NTAB);
    int* cursor = counts + 50048;
    int* perm   = cursor + 50048;
    int* srcs   = perm + E;
    int* dsts   = srcs + E;

    float* out_he = (float*)d_out;
    float* out_y  = out_he + (long long)E * DIM;

    const short* aW0hi = wt,           *aW0lo = wt + 8192;
    const short* aW1hi = wt + 16384,   *aW1lo = wt + 24576;
    const short* mW0hi = wt + 32768,   *mW0lo = wt + 65536;
    const short* mW1hi = wt + 98304,   *mW1lo = wt + 131072;
    const short* lpW1hi = wt + 163840, *lpW1lo = wt + 180224;

    detect_mode_kernel<<<1, 256, 0, stream>>>(ei, flag);
    prep_weights<<<384, 256, 0, stream>>>(aW0, aW1, mW0, mW1, lpW1, wt);
    f32_to_bf16_kernel<<<(int)(NTAB / 8 / 256), 256, 0, stream>>>(x, xb_h2b, NTAB);

    // ---- CSR build (edge structure is layer-invariant) ----
    hipMemsetAsync(counts, 0, 50048 * sizeof(int), stream);
    hist_kernel<<<1024, 256, 0, stream>>>(ei, flag, counts, E);
    scan_kernel<<<1, 1024, 0, stream>>>(counts, cursor);
    scatter_kernel<<<1024, 256, 0, stream>>>(ei, flag, cursor, perm, srcs, dsts, E);

    const int eblocks = (E + 63) / 64;
    const int nblocks = (NNODES + 63) / 64;

    // ---- layer 0 ----
    hipMemsetAsync(agg, 0, NTAB * sizeof(float), stream);
    edge_msg_sorted<<<eblocks, 256, 0, stream>>>(xb_h2b, eattr, perm, srcs, dsts,
                                                 aW0hi, aW0lo, ab0, agg, E);
    node_update_mfma<<<nblocks, 256, 0, stream>>>(agg, x, mW0hi, mW0lo, mb0, eps0, h1, h1b, 0);

    // ---- layer 1 ----
    hipMemsetAsync(agg, 0, NTAB * sizeof(float), stream);
    edge_msg_sorted<<<eblocks, 256, 0, stream>>>(h1b, eattr, perm, srcs, dsts,
                                                 aW1hi, aW1lo, ab1, agg, E);
    node_update_mfma<<<nblocks, 256, 0, stream>>>(agg, h1, mW1hi, mW1lo, mb1, eps1, nullptr, xb_h2b, 1);

    // ---- link predictor head ----
    edge_head_mfma<<<1024, 512, 0, stream>>>(xb_h2b, ei, flag, lpW1hi, lpW1lo, lpb1, lpW2, lpb2,
                                             out_he, out_y, E);
}

// Round 5
// 821.565 us; speedup vs baseline: 2.4408x; 1.6256x over previous
//
#include <hip/hip_runtime.h>
#include <math.h>

#define NNODES 50000
#define DIM 128
#define DEDGE 64

typedef __attribute__((ext_vector_type(8))) short bf16x8;
typedef __attribute__((ext_vector_type(4))) float f32x4;
typedef __attribute__((ext_vector_type(2))) float f32x2;

__device__ __forceinline__ float bf_lo(unsigned u) { return __builtin_bit_cast(float, u << 16); }
__device__ __forceinline__ float bf_hi(unsigned u) { return __builtin_bit_cast(float, u & 0xFFFF0000u); }
__device__ __forceinline__ float bf_s(short s) {
    return __builtin_bit_cast(float, ((unsigned)(unsigned short)s) << 16);
}
__device__ __forceinline__ unsigned short f2b_rtn(float f) {
    unsigned u = __builtin_bit_cast(unsigned, f);
    u += 0x7FFFu + ((u >> 16) & 1u);
    return (unsigned short)(u >> 16);
}

// ---------------------------------------------------------------------------
// edge_index dtype detection (int64 per reference vs int32 per harness doc)
// ---------------------------------------------------------------------------
__global__ void detect_mode_kernel(const void* __restrict__ ei, int* __restrict__ flag) {
    __shared__ int bad;
    if (threadIdx.x == 0) bad = 0;
    __syncthreads();
    const long long* p = (const long long*)ei;
    int localbad = 0;
    for (int i = threadIdx.x; i < 4096; i += blockDim.x) {
        long long v = p[i];
        if (v < 0 || v >= NNODES) localbad = 1;
    }
    if (localbad) atomicOr(&bad, 1);
    __syncthreads();
    if (threadIdx.x == 0) *flag = bad ? 0 : 1;   // 1 = int64 mode
}

__device__ __forceinline__ int load_idx(const void* ei, long long pos, int mode64) {
    if (mode64) return (int)((const long long*)ei)[pos];
    return ((const int*)ei)[pos];
}

// ---------------------------------------------------------------------------
// split f32 -> bf16 hi (RTZ) + bf16 lo (RTN of remainder); hi+lo ~ 2^-17 rel
// ---------------------------------------------------------------------------
__device__ __forceinline__ void split_bf16(float f, short& hi, short& lo) {
    union { float f; unsigned u; } v; v.f = f;
    unsigned uh = v.u & 0xFFFF0000u;
    hi = (short)(uh >> 16);
    union { unsigned u; float f; } hh; hh.u = uh;
    float r = f - hh.f;
    union { float f; unsigned u; } w; w.f = r;
    unsigned t = w.u + 0x7FFFu + ((w.u >> 16) & 1u);
    lo = (short)(t >> 16);
}

// ---------------------------------------------------------------------------
// prep: weights -> FRAGMENT-ORDER hi/lo bf16 tables.
// chunk c = n*NKC+kc (n: 16-col group, kc: 32-k group); lane l; elem j:
//   wt[((c*64+l)*8)+j] = W[(kc*32+(l>>4)*8+j)*128 + n*16+(l&15)]
// -> each MFMA B-frag load is one contiguous 16B/lane, 1KB/instruction.
// ---------------------------------------------------------------------------
__global__ void prep_weights(const float* __restrict__ aW0, const float* __restrict__ aW1,
                             const float* __restrict__ mW0, const float* __restrict__ mW1,
                             const float* __restrict__ lpW1, short* __restrict__ wt)
{
    int i = blockIdx.x * 256 + threadIdx.x;   // 0..98303 (384 blocks)
    const float* src; int K, hioff, looff, f;
    if (i < 8192)        { src = aW0;  K = 64;  hioff = 0;      looff = 8192;   f = i; }
    else if (i < 16384)  { src = aW1;  K = 64;  hioff = 16384;  looff = 24576;  f = i - 8192; }
    else if (i < 49152)  { src = mW0;  K = 256; hioff = 32768;  looff = 65536;  f = i - 16384; }
    else if (i < 81920)  { src = mW1;  K = 256; hioff = 98304;  looff = 131072; f = i - 49152; }
    else                 { src = lpW1; K = 128; hioff = 163840; looff = 180224; f = i - 81920; }
    const int NKC = K >> 5;
    int j = f & 7, l = (f >> 3) & 63, c = f >> 9;
    int kc = c % NKC, n = c / NKC;
    int col = n * 16 + (l & 15);
    int k = kc * 32 + ((l >> 4) << 3) + j;
    float v = src[k * DIM + col];
    short hi, lo; split_bf16(v, hi, lo);
    wt[hioff + f] = hi;
    wt[looff + f] = lo;
}

// f32 -> bf16 table conversion (coalesced, 8 elems/thread)
__global__ void f32_to_bf16_kernel(const float* __restrict__ in,
                                   unsigned short* __restrict__ out, long long n)
{
    long long i = ((long long)blockIdx.x * 256 + threadIdx.x) * 8;
    if (i >= n) return;
    f32x4 a = *(const f32x4*)(in + i);
    f32x4 b = *(const f32x4*)(in + i + 4);
    unsigned short v[8];
#pragma unroll
    for (int t = 0; t < 4; t++) { v[t] = f2b_rtn(a[t]); v[4 + t] = f2b_rtn(b[t]); }
    unsigned p0 = v[0] | ((unsigned)v[1] << 16);
    unsigned p1 = v[2] | ((unsigned)v[3] << 16);
    unsigned p2 = v[4] | ((unsigned)v[5] << 16);
    unsigned p3 = v[6] | ((unsigned)v[7] << 16);
    f32x4 pk = {__builtin_bit_cast(float, p0), __builtin_bit_cast(float, p1),
                __builtin_bit_cast(float, p2), __builtin_bit_cast(float, p3)};
    *(f32x4*)(out + i) = pk;
}

// ---------------------------------------------------------------------------
// CSR build: histogram of dst, exclusive scan, scatter to sorted order
// ---------------------------------------------------------------------------
__global__ void hist_kernel(const void* __restrict__ ei, const int* __restrict__ modep,
                            int* __restrict__ counts, int E)
{
    const int mode64 = *modep;
    for (int e = blockIdx.x * 256 + threadIdx.x; e < E; e += gridDim.x * 256)
        atomicAdd(&counts[load_idx(ei, (long long)E + e, mode64)], 1);
}

__global__ __launch_bounds__(1024) void scan_kernel(const int* __restrict__ counts,
                                                    int* __restrict__ cursor)
{
    __shared__ int part[1024];
    const int t = threadIdx.x;
    const int CH = (NNODES + 1023) / 1024;
    const int lo = t * CH, hi = min(lo + CH, NNODES);
    int s = 0;
    for (int i = lo; i < hi; i++) s += counts[i];
    part[t] = s;
    __syncthreads();
    for (int d = 1; d < 1024; d <<= 1) {
        int v = (t >= d) ? part[t - d] : 0;
        __syncthreads();
        part[t] += v;
        __syncthreads();
    }
    int run = (t == 0) ? 0 : part[t - 1];
    for (int i = lo; i < hi; i++) { cursor[i] = run; run += counts[i]; }
}

__global__ void scatter_kernel(const void* __restrict__ ei, const int* __restrict__ modep,
                               int* __restrict__ cursor, int* __restrict__ perm,
                               int* __restrict__ srcs, int* __restrict__ dsts, int E)
{
    const int mode64 = *modep;
    for (int e = blockIdx.x * 256 + threadIdx.x; e < E; e += gridDim.x * 256) {
        int d = load_idx(ei, (long long)E + e, mode64);
        int s = load_idx(ei, e, mode64);
        int pos = atomicAdd(&cursor[d], 1);
        perm[pos] = e;
        srcs[pos] = s;
        dsts[pos] = d;
    }
}

// ---------------------------------------------------------------------------
// edge message + scatter over dst-SORTED edges:
//   agg[dst] += relu(h[src] + eattr@W + b)
// wave-per-16-sorted-edges MFMA; segmented epilogue: runs of equal dst
// accumulate in registers, one scalar-atomic burst per run boundary.
// eattr read non-temporally (stream; keep node tables cached).
// ---------------------------------------------------------------------------
__global__ __launch_bounds__(256, 4) void edge_msg_sorted(
    const unsigned short* __restrict__ hb, const float* __restrict__ eattr,
    const int* __restrict__ perm, const int* __restrict__ srcs,
    const int* __restrict__ dsts,
    const short* __restrict__ Whi, const short* __restrict__ Wlo,
    const float* __restrict__ bvec, float* __restrict__ agg, int E)
{
    __shared__ float e_lds[4][16][132];
    const int lane = threadIdx.x & 63;
    const int w = threadIdx.x >> 6;
    const int lg = lane >> 4, lr = lane & 15;
    const long long p0 = ((long long)blockIdx.x * 4 + w) * 16;
    if (p0 >= E) return;

    const long long pos = (p0 + lr < E) ? (p0 + lr) : (E - 1);
    const int eid  = perm[pos];
    const int sidx = srcs[pos];
    const int didx = dsts[pos];

    f32x4 acc[8];
#pragma unroll
    for (int n = 0; n < 8; n++) {
        float b = bvec[n * 16 + lr];
        acc[n] = (f32x4){b, b, b, b};
    }
    bf16x8 ahi[2], alo[2];
#pragma unroll
    for (int kc = 0; kc < 2; kc++) {
        const float* p = eattr + (long long)eid * DEDGE + kc * 32 + lg * 8;
        f32x4 v0 = __builtin_nontemporal_load((const f32x4*)p);
        f32x4 v1 = __builtin_nontemporal_load((const f32x4*)(p + 4));
#pragma unroll
        for (int i = 0; i < 4; i++) {
            short h, l;
            split_bf16(v0[i], h, l); ahi[kc][i] = h; alo[kc][i] = l;
            split_bf16(v1[i], h, l); ahi[kc][4 + i] = h; alo[kc][4 + i] = l;
        }
    }

#pragma unroll
    for (int n = 0; n < 8; n++) {
#pragma unroll
        for (int kc = 0; kc < 2; kc++) {
            const int off = ((n * 2 + kc) * 64 + lane) * 8;
            bf16x8 bh = *(const bf16x8*)(Whi + off);
            bf16x8 bl = *(const bf16x8*)(Wlo + off);
            acc[n] = __builtin_amdgcn_mfma_f32_16x16x32_bf16(ahi[kc], bh, acc[n], 0, 0, 0);
            acc[n] = __builtin_amdgcn_mfma_f32_16x16x32_bf16(alo[kc], bh, acc[n], 0, 0, 0);
            acc[n] = __builtin_amdgcn_mfma_f32_16x16x32_bf16(ahi[kc], bl, acc[n], 0, 0, 0);
        }
    }
    // D layout: col = n*16+lr, row = lg*4+r
#pragma unroll
    for (int n = 0; n < 8; n++)
#pragma unroll
        for (int r = 0; r < 4; r++)
            e_lds[w][lg * 4 + r][n * 16 + lr] = acc[n][r];

    // segmented epilogue: lane owns cols {2l,2l+1}
    float a0 = 0.f, a1 = 0.f;
    int prev = -1;
    for (int r = 0; r < 16; r++) {
        if (p0 + r >= E) break;
        int di = __shfl(didx, r);
        int si = __shfl(sidx, r);
        f32x2 ev = *(const f32x2*)&e_lds[w][r][2 * lane];
        unsigned u = *(const unsigned*)&hb[(long long)si * DIM + 2 * lane];
        float m0 = fmaxf(ev.x + bf_lo(u), 0.f);
        float m1 = fmaxf(ev.y + bf_hi(u), 0.f);
        if (di != prev && prev >= 0) {
            float* d = &agg[(long long)prev * DIM + 2 * lane];
            unsafeAtomicAdd(d, a0);
            unsafeAtomicAdd(d + 1, a1);
            a0 = 0.f; a1 = 0.f;
        }
        a0 += m0; a1 += m1; prev = di;
    }
    if (prev >= 0) {
        float* d = &agg[(long long)prev * DIM + 2 * lane];
        unsafeAtomicAdd(d, a0);
        unsafeAtomicAdd(d + 1, a1);
    }
}

// ---------------------------------------------------------------------------
// GIN update: hout = act([agg | (1+eps)*h] @ W(256x128) + b), wave-per-16-nodes
// optionally writes f32 and/or bf16 (LDS-staged, coalesced) copies.
// ---------------------------------------------------------------------------
__global__ __launch_bounds__(256, 4) void node_update_mfma(
    const float* __restrict__ agg, const float* __restrict__ h,
    const short* __restrict__ Whi, const short* __restrict__ Wlo,
    const float* __restrict__ bvec, const float* __restrict__ epsp,
    float* __restrict__ houtf, unsigned short* __restrict__ houtb, int relu_flag)
{
    __shared__ float st[4][16][132];
    const int lane = threadIdx.x & 63;
    const int w = threadIdx.x >> 6;
    const int lg = lane >> 4, lr = lane & 15;
    const int n0 = (blockIdx.x * 4 + w) * 16;
    if (n0 >= NNODES) return;
    const float s = 1.0f + epsp[0];
    const int arow = (n0 + lr < NNODES) ? (n0 + lr) : (NNODES - 1);

    f32x4 acc[8];
#pragma unroll
    for (int n = 0; n < 8; n++) {
        float b = bvec[n * 16 + lr];
        acc[n] = (f32x4){b, b, b, b};
    }
#pragma unroll
    for (int kc = 0; kc < 8; kc++) {
        const int k = kc * 32 + lg * 8;
        float buf[8];
        if (k < 128) {
            f32x4 v0 = *(const f32x4*)(agg + (long long)arow * DIM + k);
            f32x4 v1 = *(const f32x4*)(agg + (long long)arow * DIM + k + 4);
#pragma unroll
            for (int i = 0; i < 4; i++) { buf[i] = v0[i]; buf[4 + i] = v1[i]; }
        } else {
            f32x4 v0 = *(const f32x4*)(h + (long long)arow * DIM + (k - 128));
            f32x4 v1 = *(const f32x4*)(h + (long long)arow * DIM + (k - 128) + 4);
#pragma unroll
            for (int i = 0; i < 4; i++) { buf[i] = s * v0[i]; buf[4 + i] = s * v1[i]; }
        }
        bf16x8 ahi, alo;
#pragma unroll
        for (int i = 0; i < 8; i++) { short hh, ll; split_bf16(buf[i], hh, ll); ahi[i] = hh; alo[i] = ll; }
#pragma unroll
        for (int n = 0; n < 8; n++) {
            const int off = ((n * 8 + kc) * 64 + lane) * 8;
            bf16x8 bh = *(const bf16x8*)(Whi + off);
            bf16x8 bl = *(const bf16x8*)(Wlo + off);
            acc[n] = __builtin_amdgcn_mfma_f32_16x16x32_bf16(ahi, bh, acc[n], 0, 0, 0);
            acc[n] = __builtin_amdgcn_mfma_f32_16x16x32_bf16(alo, bh, acc[n], 0, 0, 0);
            acc[n] = __builtin_amdgcn_mfma_f32_16x16x32_bf16(ahi, bl, acc[n], 0, 0, 0);
        }
    }
#pragma unroll
    for (int n = 0; n < 8; n++) {
#pragma unroll
        for (int r = 0; r < 4; r++) {
            float z = acc[n][r];
            z = relu_flag ? fmaxf(z, 0.f) : (z > 0.f ? z : 0.2f * z);
            int row = n0 + lg * 4 + r;
            if (houtf && row < NNODES)
                houtf[(long long)row * DIM + n * 16 + lr] = z;
            st[w][lg * 4 + r][n * 16 + lr] = z;
        }
    }
    if (houtb) {
        for (int r = 0; r < 16; r++) {
            int row = n0 + r;
            if (row >= NNODES) break;
            f32x2 v = *(const f32x2*)&st[w][r][2 * lane];
            unsigned pk = (unsigned)f2b_rtn(v.x) | ((unsigned)f2b_rtn(v.y) << 16);
            *(unsigned*)&houtb[(long long)row * DIM + 2 * lane] = pk;
        }
    }
}

// ---------------------------------------------------------------------------
// edge head: he = h[src]*h[dst] from bf16 table (exact f32 product),
// nt-write he f32; z = leaky(he@W1+b1); logits = z@W2+b2; yhat = softmax2.
// 256-thread blocks, no LDS; W1 hi/lo read from fragment-ordered global
// tables (contiguous 1KB/instruction, L2-resident).
// ---------------------------------------------------------------------------
__global__ __launch_bounds__(256, 6) void edge_head_mfma(
    const unsigned short* __restrict__ hb, const void* __restrict__ ei,
    const int* __restrict__ modep,
    const short* __restrict__ W1hi, const short* __restrict__ W1lo,
    const float* __restrict__ b1, const float* __restrict__ W2,
    const float* __restrict__ b2,
    float* __restrict__ out_he, float* __restrict__ out_y, int E)
{
    const int mode64 = *modep;
    const int lane = threadIdx.x & 63;
    const int w = threadIdx.x >> 6;
    const int lg = lane >> 4, lr = lane & 15;
    const long long e0 = ((long long)blockIdx.x * 4 + w) * 16;
    if (e0 >= E) return;
    const long long erow = (e0 + lr < E) ? (e0 + lr) : (E - 1);
    int si = load_idx(ei, erow, mode64);
    int di = load_idx(ei, (long long)E + erow, mode64);

    f32x4 acc[8];
#pragma unroll
    for (int n = 0; n < 8; n++) {
        float b = b1[n * 16 + lr];
        acc[n] = (f32x4){b, b, b, b};
    }
    bf16x8 ahi[4], alo[4];
#pragma unroll
    for (int kc = 0; kc < 4; kc++) {
        const int k = kc * 32 + lg * 8;
        bf16x8 hs = *(const bf16x8*)(hb + (long long)si * DIM + k);
        bf16x8 hd = *(const bf16x8*)(hb + (long long)di * DIM + k);
        f32x4 p0, p1;
#pragma unroll
        for (int i = 0; i < 4; i++) {
            p0[i] = bf_s(hs[i]) * bf_s(hd[i]);
            p1[i] = bf_s(hs[4 + i]) * bf_s(hd[4 + i]);
        }
        if (e0 + lr < E) {
            __builtin_nontemporal_store(p0, (f32x4*)(out_he + erow * DIM + k));
            __builtin_nontemporal_store(p1, (f32x4*)(out_he + erow * DIM + k + 4));
        }
#pragma unroll
        for (int i = 0; i < 4; i++) {
            short hh, ll;
            split_bf16(p0[i], hh, ll); ahi[kc][i] = hh; alo[kc][i] = ll;
            split_bf16(p1[i], hh, ll); ahi[kc][4 + i] = hh; alo[kc][4 + i] = ll;
        }
    }
#pragma unroll
    for (int n = 0; n < 8; n++) {
#pragma unroll
        for (int kc = 0; kc < 4; kc++) {
            const int off = ((n * 4 + kc) * 64 + lane) * 8;
            bf16x8 bh = *(const bf16x8*)(W1hi + off);
            bf16x8 bl = *(const bf16x8*)(W1lo + off);
            acc[n] = __builtin_amdgcn_mfma_f32_16x16x32_bf16(ahi[kc], bh, acc[n], 0, 0, 0);
            acc[n] = __builtin_amdgcn_mfma_f32_16x16x32_bf16(alo[kc], bh, acc[n], 0, 0, 0);
            acc[n] = __builtin_amdgcn_mfma_f32_16x16x32_bf16(ahi[kc], bl, acc[n], 0, 0, 0);
        }
    }
    // logits: leaky(z) dotted with W2 cols, reduce over the 16 cols (lr)
    float q0[4] = {0.f, 0.f, 0.f, 0.f}, q1[4] = {0.f, 0.f, 0.f, 0.f};
#pragma unroll
    for (int n = 0; n < 8; n++) {
        float w2a = W2[(n * 16 + lr) * 2 + 0];
        float w2b = W2[(n * 16 + lr) * 2 + 1];
#pragma unroll
        for (int r = 0; r < 4; r++) {
            float z = acc[n][r];
            z = z > 0.f ? z : 0.2f * z;
            q0[r] = fmaf(z, w2a, q0[r]);
            q1[r] = fmaf(z, w2b, q1[r]);
        }
    }
#pragma unroll
    for (int m = 1; m < 16; m <<= 1) {
#pragma unroll
        for (int r = 0; r < 4; r++) {
            q0[r] += __shfl_xor(q0[r], m);
            q1[r] += __shfl_xor(q1[r], m);
        }
    }
    if (lr == 0) {
        float c0 = b2[0], c1 = b2[1];
#pragma unroll
        for (int r = 0; r < 4; r++) {
            long long e = e0 + lg * 4 + r;
            if (e < E) {
                float l0 = q0[r] + c0, l1 = q1[r] + c1;
                float mx = fmaxf(l0, l1);
                float x0 = expf(l0 - mx), x1 = expf(l1 - mx);
                float inv = 1.f / (x0 + x1);
                __builtin_nontemporal_store(x0 * inv, &out_y[e * 2 + 0]);
                __builtin_nontemporal_store(x1 * inv, &out_y[e * 2 + 1]);
            }
        }
    }
}

extern "C" void kernel_launch(void* const* d_in, const int* in_sizes, int n_in,
                              void* d_out, int out_size, void* d_ws, size_t ws_size,
                              hipStream_t stream)
{
    const float* x     = (const float*)d_in[0];
    const void*  ei    = d_in[1];
    const float* eattr = (const float*)d_in[2];
    const float* aW0   = (const float*)d_in[3];
    const float* ab0   = (const float*)d_in[4];
    const float* mW0   = (const float*)d_in[5];
    const float* mb0   = (const float*)d_in[6];
    const float* eps0  = (const float*)d_in[7];
    const float* aW1   = (const float*)d_in[8];
    const float* ab1   = (const float*)d_in[9];
    const float* mW1   = (const float*)d_in[10];
    const float* mb1   = (const float*)d_in[11];
    const float* eps1  = (const float*)d_in[12];
    const float* lpW1  = (const float*)d_in[13];
    const float* lpb1  = (const float*)d_in[14];
    const float* lpW2  = (const float*)d_in[15];
    const float* lpb2  = (const float*)d_in[16];

    const int E = in_sizes[1] / 2;
    const long long NTAB = (long long)NNODES * DIM;   // 6.4M

    float* wsf  = (float*)d_ws;
    int*   flag = (int*)d_ws;
    float* agg  = wsf + 64;
    float* h1   = agg + NTAB;
    short* wt   = (short*)(h1 + NTAB);
    unsigned short* xb_h2b = (unsigned short*)(wt + 196608); // x bf16, later h2 bf16
    unsigned short* h1b    = xb_h2b + NTAB;
    int* counts = (int*)(h1b + NTAB);
    int* cursor = counts + 50048;
    int* perm   = cursor + 50048;
    int* srcs   = perm + E;
    int* dsts   = srcs + E;

    float* out_he = (float*)d_out;
    float* out_y  = out_he + (long long)E * DIM;

    const short* aW0hi = wt,           *aW0lo = wt + 8192;
    const short* aW1hi = wt + 16384,   *aW1lo = wt + 24576;
    const short* mW0hi = wt + 32768,   *mW0lo = wt + 65536;
    const short* mW1hi = wt + 98304,   *mW1lo = wt + 131072;
    const short* lpW1hi = wt + 163840, *lpW1lo = wt + 180224;

    detect_mode_kernel<<<1, 256, 0, stream>>>(ei, flag);
    prep_weights<<<384, 256, 0, stream>>>(aW0, aW1, mW0, mW1, lpW1, wt);
    f32_to_bf16_kernel<<<(int)(NTAB / 8 / 256), 256, 0, stream>>>(x, xb_h2b, NTAB);

    // ---- CSR build (edge structure is layer-invariant) ----
    hipMemsetAsync(counts, 0, 50048 * sizeof(int), stream);
    hist_kernel<<<1024, 256, 0, stream>>>(ei, flag, counts, E);
    scan_kernel<<<1, 1024, 0, stream>>>(counts, cursor);
    scatter_kernel<<<1024, 256, 0, stream>>>(ei, flag, cursor, perm, srcs, dsts, E);

    const int eblocks = (E + 63) / 64;
    const int nblocks = (NNODES + 63) / 64;

    // ---- layer 0 ----
    hipMemsetAsync(agg, 0, NTAB * sizeof(float), stream);
    edge_msg_sorted<<<eblocks, 256, 0, stream>>>(xb_h2b, eattr, perm, srcs, dsts,
                                                 aW0hi, aW0lo, ab0, agg, E);
    node_update_mfma<<<nblocks, 256, 0, stream>>>(agg, x, mW0hi, mW0lo, mb0, eps0, h1, h1b, 0);

    // ---- layer 1 ----
    hipMemsetAsync(agg, 0, NTAB * sizeof(float), stream);
    edge_msg_sorted<<<eblocks, 256, 0, stream>>>(h1b, eattr, perm, srcs, dsts,
                                                 aW1hi, aW1lo, ab1, agg, E);
    node_update_mfma<<<nblocks, 256, 0, stream>>>(agg, h1, mW1hi, mW1lo, mb1, eps1, nullptr, xb_h2b, 1);

    // ---- link predictor head ----
    edge_head_mfma<<<eblocks, 256, 0, stream>>>(xb_h2b, ei, flag, lpW1hi, lpW1lo, lpb1, lpW2, lpb2,
                                                out_he, out_y, E);
}

// Round 6
// 727.048 us; speedup vs baseline: 2.7581x; 1.1300x over previous
//
#include <hip/hip_runtime.h>
#include <math.h>

#define NNODES 50000
#define DIM 128
#define DEDGE 64

typedef __attribute__((ext_vector_type(8))) short bf16x8;
typedef __attribute__((ext_vector_type(4))) float f32x4;
typedef __attribute__((ext_vector_type(2))) float f32x2;

__device__ __forceinline__ float bf_lo(unsigned u) { return __builtin_bit_cast(float, u << 16); }
__device__ __forceinline__ float bf_hi(unsigned u) { return __builtin_bit_cast(float, u & 0xFFFF0000u); }
__device__ __forceinline__ float bf_s(short s) {
    return __builtin_bit_cast(float, ((unsigned)(unsigned short)s) << 16);
}
__device__ __forceinline__ unsigned short f2b_rtn(float f) {
    unsigned u = __builtin_bit_cast(unsigned, f);
    u += 0x7FFFu + ((u >> 16) & 1u);
    return (unsigned short)(u >> 16);
}

// ---------------------------------------------------------------------------
// edge_index dtype detection (int64 per reference vs int32 per harness doc)
// ---------------------------------------------------------------------------
__global__ void detect_mode_kernel(const void* __restrict__ ei, int* __restrict__ flag) {
    __shared__ int bad;
    if (threadIdx.x == 0) bad = 0;
    __syncthreads();
    const long long* p = (const long long*)ei;
    int localbad = 0;
    for (int i = threadIdx.x; i < 4096; i += blockDim.x) {
        long long v = p[i];
        if (v < 0 || v >= NNODES) localbad = 1;
    }
    if (localbad) atomicOr(&bad, 1);
    __syncthreads();
    if (threadIdx.x == 0) *flag = bad ? 0 : 1;   // 1 = int64 mode
}

__device__ __forceinline__ int load_idx(const void* ei, long long pos, int mode64) {
    if (mode64) return (int)((const long long*)ei)[pos];
    return ((const int*)ei)[pos];
}

// ---------------------------------------------------------------------------
// split f32 -> bf16 hi (RTZ) + bf16 lo (RTN of remainder); hi+lo ~ 2^-17 rel
// ---------------------------------------------------------------------------
__device__ __forceinline__ void split_bf16(float f, short& hi, short& lo) {
    union { float f; unsigned u; } v; v.f = f;
    unsigned uh = v.u & 0xFFFF0000u;
    hi = (short)(uh >> 16);
    union { unsigned u; float f; } hh; hh.u = uh;
    float r = f - hh.f;
    union { float f; unsigned u; } w; w.f = r;
    unsigned t = w.u + 0x7FFFu + ((w.u >> 16) & 1u);
    lo = (short)(t >> 16);
}

// ---------------------------------------------------------------------------
// prep: weights -> FRAGMENT-ORDER hi/lo bf16 tables; (1+eps) folded exactly
// into the h-half (k>=128) of the GIN weights.
// ---------------------------------------------------------------------------
__global__ void prep_weights(const float* __restrict__ aW0, const float* __restrict__ aW1,
                             const float* __restrict__ mW0, const float* __restrict__ mW1,
                             const float* __restrict__ lpW1,
                             const float* __restrict__ eps0p, const float* __restrict__ eps1p,
                             short* __restrict__ wt)
{
    int i = blockIdx.x * 256 + threadIdx.x;   // 0..98303 (384 blocks)
    const float* src; int K, hioff, looff, f;
    float scale_hi = 1.0f;   // applied to k>=128 rows (GIN h-half)
    if (i < 8192)        { src = aW0;  K = 64;  hioff = 0;      looff = 8192;   f = i; }
    else if (i < 16384)  { src = aW1;  K = 64;  hioff = 16384;  looff = 24576;  f = i - 8192; }
    else if (i < 49152)  { src = mW0;  K = 256; hioff = 32768;  looff = 65536;  f = i - 16384;
                           scale_hi = 1.0f + eps0p[0]; }
    else if (i < 81920)  { src = mW1;  K = 256; hioff = 98304;  looff = 131072; f = i - 49152;
                           scale_hi = 1.0f + eps1p[0]; }
    else                 { src = lpW1; K = 128; hioff = 163840; looff = 180224; f = i - 81920; }
    const int NKC = K >> 5;
    int j = f & 7, l = (f >> 3) & 63, c = f >> 9;
    int kc = c % NKC, n = c / NKC;
    int col = n * 16 + (l & 15);
    int k = kc * 32 + ((l >> 4) << 3) + j;
    float v = src[k * DIM + col];
    if (k >= 128) v *= scale_hi;
    short hi, lo; split_bf16(v, hi, lo);
    wt[hioff + f] = hi;
    wt[looff + f] = lo;
}

// f32 -> bf16 table conversion (coalesced, 8 elems/thread)
__global__ void f32_to_bf16_kernel(const float* __restrict__ in,
                                   unsigned short* __restrict__ out, long long n)
{
    long long i = ((long long)blockIdx.x * 256 + threadIdx.x) * 8;
    if (i >= n) return;
    f32x4 a = *(const f32x4*)(in + i);
    f32x4 b = *(const f32x4*)(in + i + 4);
    unsigned short v[8];
#pragma unroll
    for (int t = 0; t < 4; t++) { v[t] = f2b_rtn(a[t]); v[4 + t] = f2b_rtn(b[t]); }
    unsigned p0 = v[0] | ((unsigned)v[1] << 16);
    unsigned p1 = v[2] | ((unsigned)v[3] << 16);
    unsigned p2 = v[4] | ((unsigned)v[5] << 16);
    unsigned p3 = v[6] | ((unsigned)v[7] << 16);
    f32x4 pk = {__builtin_bit_cast(float, p0), __builtin_bit_cast(float, p1),
                __builtin_bit_cast(float, p2), __builtin_bit_cast(float, p3)};
    *(f32x4*)(out + i) = pk;
}

// ---------------------------------------------------------------------------
// CSR build: histogram of dst, exclusive scan, scatter to sorted order
// ---------------------------------------------------------------------------
__global__ void hist_kernel(const void* __restrict__ ei, const int* __restrict__ modep,
                            int* __restrict__ counts, int E)
{
    const int mode64 = *modep;
    for (int e = blockIdx.x * 256 + threadIdx.x; e < E; e += gridDim.x * 256)
        atomicAdd(&counts[load_idx(ei, (long long)E + e, mode64)], 1);
}

__global__ __launch_bounds__(1024) void scan_kernel(const int* __restrict__ counts,
                                                    int* __restrict__ cursor)
{
    __shared__ int part[1024];
    const int t = threadIdx.x;
    const int CH = (NNODES + 1023) / 1024;
    const int lo = t * CH, hi = min(lo + CH, NNODES);
    int s = 0;
    for (int i = lo; i < hi; i++) s += counts[i];
    part[t] = s;
    __syncthreads();
    for (int d = 1; d < 1024; d <<= 1) {
        int v = (t >= d) ? part[t - d] : 0;
        __syncthreads();
        part[t] += v;
        __syncthreads();
    }
    int run = (t == 0) ? 0 : part[t - 1];
    for (int i = lo; i < hi; i++) { cursor[i] = run; run += counts[i]; }
}

__global__ void scatter_kernel(const void* __restrict__ ei, const int* __restrict__ modep,
                               int* __restrict__ cursor, int* __restrict__ perm,
                               int* __restrict__ srcs, int* __restrict__ dsts, int E)
{
    const int mode64 = *modep;
    for (int e = blockIdx.x * 256 + threadIdx.x; e < E; e += gridDim.x * 256) {
        int d = load_idx(ei, (long long)E + e, mode64);
        int s = load_idx(ei, e, mode64);
        int pos = atomicAdd(&cursor[d], 1);
        perm[pos] = e;
        srcs[pos] = s;
        dsts[pos] = d;
    }
}

// ---------------------------------------------------------------------------
// eattr -> bf16, permuted into dst-sorted order: eattrs[pos] = bf16(eattr[perm[pos]])
// Subsequent edge_msg reads are LINEAR nt streams (no gather, no perm).
// ---------------------------------------------------------------------------
__global__ void eattr_sort_bf16(const float* __restrict__ eattr, const int* __restrict__ perm,
                                unsigned short* __restrict__ out, int E)
{
    long long i = ((long long)blockIdx.x * 256 + threadIdx.x) * 8;
    if (i >= (long long)E * DEDGE) return;
    long long pos = i >> 6;
    int k = (int)(i & 63);
    long long eid = perm[pos];
    f32x4 a = *(const f32x4*)(eattr + eid * DEDGE + k);
    f32x4 b = *(const f32x4*)(eattr + eid * DEDGE + k + 4);
    unsigned short v[8];
#pragma unroll
    for (int t = 0; t < 4; t++) { v[t] = f2b_rtn(a[t]); v[4 + t] = f2b_rtn(b[t]); }
    unsigned p0 = v[0] | ((unsigned)v[1] << 16);
    unsigned p1 = v[2] | ((unsigned)v[3] << 16);
    unsigned p2 = v[4] | ((unsigned)v[5] << 16);
    unsigned p3 = v[6] | ((unsigned)v[7] << 16);
    f32x4 pk = {__builtin_bit_cast(float, p0), __builtin_bit_cast(float, p1),
                __builtin_bit_cast(float, p2), __builtin_bit_cast(float, p3)};
    __builtin_nontemporal_store(pk, (f32x4*)(out + i));
}

// ---------------------------------------------------------------------------
// edge message + scatter over dst-SORTED edges:
//   agg[dst] += relu(h[src] + eattr@W + b)
// A = sorted bf16 eattr (linear nt 16B frag loads); B = hi/lo frag-order W
// (2 MFMAs per frag). Epilogue: fully unrolled segmented reduction with
// hoisted gathers; one scalar-atomic pair per dst-run boundary.
// ---------------------------------------------------------------------------
__global__ __launch_bounds__(256, 4) void edge_msg_sorted(
    const unsigned short* __restrict__ hb, const unsigned short* __restrict__ eattrs,
    const int* __restrict__ srcs, const int* __restrict__ dsts,
    const short* __restrict__ Whi, const short* __restrict__ Wlo,
    const float* __restrict__ bvec, float* __restrict__ agg, int E)
{
    __shared__ float e_lds[4][16][132];
    const int lane = threadIdx.x & 63;
    const int w = threadIdx.x >> 6;
    const int lg = lane >> 4, lr = lane & 15;
    const long long p0 = ((long long)blockIdx.x * 4 + w) * 16;
    if (p0 >= E) return;

    const long long pos = (p0 + lr < E) ? (p0 + lr) : (E - 1);
    const int sidx = srcs[pos];
    const int didx = dsts[pos];

    f32x4 acc[8];
#pragma unroll
    for (int n = 0; n < 8; n++) {
        float b = bvec[n * 16 + lr];
        acc[n] = (f32x4){b, b, b, b};
    }
    bf16x8 a[2];
#pragma unroll
    for (int kc = 0; kc < 2; kc++)
        a[kc] = __builtin_nontemporal_load(
            (const bf16x8*)(eattrs + pos * DEDGE + kc * 32 + lg * 8));

#pragma unroll
    for (int n = 0; n < 8; n++) {
#pragma unroll
        for (int kc = 0; kc < 2; kc++) {
            const int off = ((n * 2 + kc) * 64 + lane) * 8;
            bf16x8 bh = *(const bf16x8*)(Whi + off);
            bf16x8 bl = *(const bf16x8*)(Wlo + off);
            acc[n] = __builtin_amdgcn_mfma_f32_16x16x32_bf16(a[kc], bh, acc[n], 0, 0, 0);
            acc[n] = __builtin_amdgcn_mfma_f32_16x16x32_bf16(a[kc], bl, acc[n], 0, 0, 0);
        }
    }
    // D layout: col = n*16+lr, row = lg*4+r
#pragma unroll
    for (int n = 0; n < 8; n++)
#pragma unroll
        for (int r = 0; r < 4; r++)
            e_lds[w][lg * 4 + r][n * 16 + lr] = acc[n][r];

    if (p0 + 16 <= E) {
        // full-tile fast path: hoist all gathers/shfls, unrolled segmented sum
        unsigned gu[16];
        int dvs[16];
#pragma unroll
        for (int r = 0; r < 16; r++) {
            int si = __shfl(sidx, r);
            gu[r] = *(const unsigned*)&hb[(long long)si * DIM + 2 * lane];
        }
#pragma unroll
        for (int r = 0; r < 16; r++) dvs[r] = __shfl(didx, r);
        float a0 = 0.f, a1 = 0.f;
#pragma unroll
        for (int r = 0; r < 16; r++) {
            f32x2 ev = *(const f32x2*)&e_lds[w][r][2 * lane];
            float m0 = fmaxf(ev.x + bf_lo(gu[r]), 0.f);
            float m1 = fmaxf(ev.y + bf_hi(gu[r]), 0.f);
            if (r > 0 && dvs[r] != dvs[r - 1]) {
                float* d = &agg[(long long)dvs[r - 1] * DIM + 2 * lane];
                unsafeAtomicAdd(d, a0);
                unsafeAtomicAdd(d + 1, a1);
                a0 = 0.f; a1 = 0.f;
            }
            a0 += m0; a1 += m1;
        }
        float* d = &agg[(long long)dvs[15] * DIM + 2 * lane];
        unsafeAtomicAdd(d, a0);
        unsafeAtomicAdd(d + 1, a1);
    } else {
        float a0 = 0.f, a1 = 0.f;
        int prev = -1;
        for (int r = 0; r < 16; r++) {
            if (p0 + r >= E) break;
            int di = __shfl(didx, r);
            int si = __shfl(sidx, r);
            f32x2 ev = *(const f32x2*)&e_lds[w][r][2 * lane];
            unsigned u = *(const unsigned*)&hb[(long long)si * DIM + 2 * lane];
            float m0 = fmaxf(ev.x + bf_lo(u), 0.f);
            float m1 = fmaxf(ev.y + bf_hi(u), 0.f);
            if (di != prev && prev >= 0) {
                float* d = &agg[(long long)prev * DIM + 2 * lane];
                unsafeAtomicAdd(d, a0);
                unsafeAtomicAdd(d + 1, a1);
                a0 = 0.f; a1 = 0.f;
            }
            a0 += m0; a1 += m1; prev = di;
        }
        if (prev >= 0) {
            float* d = &agg[(long long)prev * DIM + 2 * lane];
            unsafeAtomicAdd(d, a0);
            unsafeAtomicAdd(d + 1, a1);
        }
    }
}

// ---------------------------------------------------------------------------
// GIN update: houtb = bf16(act([agg | (1+eps)*h] @ W + b)); eps pre-folded
// into W's h-half. agg part hi/lo (3 MFMA), h part pure bf16 (2 MFMA).
// ---------------------------------------------------------------------------
__global__ __launch_bounds__(256, 4) void node_update_mfma(
    const float* __restrict__ agg, const unsigned short* __restrict__ hb,
    const short* __restrict__ Whi, const short* __restrict__ Wlo,
    const float* __restrict__ bvec,
    unsigned short* __restrict__ houtb, int relu_flag)
{
    __shared__ float st[4][16][132];
    const int lane = threadIdx.x & 63;
    const int w = threadIdx.x >> 6;
    const int lg = lane >> 4, lr = lane & 15;
    const int n0 = (blockIdx.x * 4 + w) * 16;
    if (n0 >= NNODES) return;
    const int arow = (n0 + lr < NNODES) ? (n0 + lr) : (NNODES - 1);

    f32x4 acc[8];
#pragma unroll
    for (int n = 0; n < 8; n++) {
        float b = bvec[n * 16 + lr];
        acc[n] = (f32x4){b, b, b, b};
    }
#pragma unroll
    for (int kc = 0; kc < 8; kc++) {
        if (kc < 4) {
            const int k = kc * 32 + lg * 8;
            f32x4 v0 = *(const f32x4*)(agg + (long long)arow * DIM + k);
            f32x4 v1 = *(const f32x4*)(agg + (long long)arow * DIM + k + 4);
            bf16x8 ahi, alo;
#pragma unroll
            for (int i = 0; i < 4; i++) {
                short hh, ll;
                split_bf16(v0[i], hh, ll); ahi[i] = hh; alo[i] = ll;
                split_bf16(v1[i], hh, ll); ahi[4 + i] = hh; alo[4 + i] = ll;
            }
#pragma unroll
            for (int n = 0; n < 8; n++) {
                const int off = ((n * 8 + kc) * 64 + lane) * 8;
                bf16x8 bh = *(const bf16x8*)(Whi + off);
                bf16x8 bl = *(const bf16x8*)(Wlo + off);
                acc[n] = __builtin_amdgcn_mfma_f32_16x16x32_bf16(ahi, bh, acc[n], 0, 0, 0);
                acc[n] = __builtin_amdgcn_mfma_f32_16x16x32_bf16(alo, bh, acc[n], 0, 0, 0);
                acc[n] = __builtin_amdgcn_mfma_f32_16x16x32_bf16(ahi, bl, acc[n], 0, 0, 0);
            }
        } else {
            bf16x8 ah = *(const bf16x8*)(hb + (long long)arow * DIM + (kc - 4) * 32 + lg * 8);
#pragma unroll
            for (int n = 0; n < 8; n++) {
                const int off = ((n * 8 + kc) * 64 + lane) * 8;
                bf16x8 bh = *(const bf16x8*)(Whi + off);
                bf16x8 bl = *(const bf16x8*)(Wlo + off);
                acc[n] = __builtin_amdgcn_mfma_f32_16x16x32_bf16(ah, bh, acc[n], 0, 0, 0);
                acc[n] = __builtin_amdgcn_mfma_f32_16x16x32_bf16(ah, bl, acc[n], 0, 0, 0);
            }
        }
    }
#pragma unroll
    for (int n = 0; n < 8; n++) {
#pragma unroll
        for (int r = 0; r < 4; r++) {
            float z = acc[n][r];
            z = relu_flag ? fmaxf(z, 0.f) : (z > 0.f ? z : 0.2f * z);
            st[w][lg * 4 + r][n * 16 + lr] = z;
        }
    }
    for (int r = 0; r < 16; r++) {
        int row = n0 + r;
        if (row >= NNODES) break;
        f32x2 v = *(const f32x2*)&st[w][r][2 * lane];
        unsigned pk = (unsigned)f2b_rtn(v.x) | ((unsigned)f2b_rtn(v.y) << 16);
        *(unsigned*)&houtb[(long long)row * DIM + 2 * lane] = pk;
    }
}

// ---------------------------------------------------------------------------
// edge head: he = h[src]*h[dst] from bf16 table (exact f32 product),
// nt-write he f32; z = leaky(he@W1+b1); logits = z@W2+b2; yhat = softmax2.
// ---------------------------------------------------------------------------
__global__ __launch_bounds__(256, 6) void edge_head_mfma(
    const unsigned short* __restrict__ hb, const void* __restrict__ ei,
    const int* __restrict__ modep,
    const short* __restrict__ W1hi, const short* __restrict__ W1lo,
    const float* __restrict__ b1, const float* __restrict__ W2,
    const float* __restrict__ b2,
    float* __restrict__ out_he, float* __restrict__ out_y, int E)
{
    const int mode64 = *modep;
    const int lane = threadIdx.x & 63;
    const int w = threadIdx.x >> 6;
    const int lg = lane >> 4, lr = lane & 15;
    const long long e0 = ((long long)blockIdx.x * 4 + w) * 16;
    if (e0 >= E) return;
    const long long erow = (e0 + lr < E) ? (e0 + lr) : (E - 1);
    int si = load_idx(ei, erow, mode64);
    int di = load_idx(ei, (long long)E + erow, mode64);

    f32x4 acc[8];
#pragma unroll
    for (int n = 0; n < 8; n++) {
        float b = b1[n * 16 + lr];
        acc[n] = (f32x4){b, b, b, b};
    }
    bf16x8 ahi[4], alo[4];
#pragma unroll
    for (int kc = 0; kc < 4; kc++) {
        const int k = kc * 32 + lg * 8;
        bf16x8 hs = *(const bf16x8*)(hb + (long long)si * DIM + k);
        bf16x8 hd = *(const bf16x8*)(hb + (long long)di * DIM + k);
        f32x4 p0, p1;
#pragma unroll
        for (int i = 0; i < 4; i++) {
            p0[i] = bf_s(hs[i]) * bf_s(hd[i]);
            p1[i] = bf_s(hs[4 + i]) * bf_s(hd[4 + i]);
        }
        if (e0 + lr < E) {
            __builtin_nontemporal_store(p0, (f32x4*)(out_he + erow * DIM + k));
            __builtin_nontemporal_store(p1, (f32x4*)(out_he + erow * DIM + k + 4));
        }
#pragma unroll
        for (int i = 0; i < 4; i++) {
            short hh, ll;
            split_bf16(p0[i], hh, ll); ahi[kc][i] = hh; alo[kc][i] = ll;
            split_bf16(p1[i], hh, ll); ahi[kc][4 + i] = hh; alo[kc][4 + i] = ll;
        }
    }
#pragma unroll
    for (int n = 0; n < 8; n++) {
#pragma unroll
        for (int kc = 0; kc < 4; kc++) {
            const int off = ((n * 4 + kc) * 64 + lane) * 8;
            bf16x8 bh = *(const bf16x8*)(W1hi + off);
            bf16x8 bl = *(const bf16x8*)(W1lo + off);
            acc[n] = __builtin_amdgcn_mfma_f32_16x16x32_bf16(ahi[kc], bh, acc[n], 0, 0, 0);
            acc[n] = __builtin_amdgcn_mfma_f32_16x16x32_bf16(alo[kc], bh, acc[n], 0, 0, 0);
            acc[n] = __builtin_amdgcn_mfma_f32_16x16x32_bf16(ahi[kc], bl, acc[n], 0, 0, 0);
        }
    }
    float q0[4] = {0.f, 0.f, 0.f, 0.f}, q1[4] = {0.f, 0.f, 0.f, 0.f};
#pragma unroll
    for (int n = 0; n < 8; n++) {
        float w2a = W2[(n * 16 + lr) * 2 + 0];
        float w2b = W2[(n * 16 + lr) * 2 + 1];
#pragma unroll
        for (int r = 0; r < 4; r++) {
            float z = acc[n][r];
            z = z > 0.f ? z : 0.2f * z;
            q0[r] = fmaf(z, w2a, q0[r]);
            q1[r] = fmaf(z, w2b, q1[r]);
        }
    }
#pragma unroll
    for (int m = 1; m < 16; m <<= 1) {
#pragma unroll
        for (int r = 0; r < 4; r++) {
            q0[r] += __shfl_xor(q0[r], m);
            q1[r] += __shfl_xor(q1[r], m);
        }
    }
    if (lr == 0) {
        float c0 = b2[0], c1 = b2[1];
#pragma unroll
        for (int r = 0; r < 4; r++) {
            long long e = e0 + lg * 4 + r;
            if (e < E) {
                float l0 = q0[r] + c0, l1 = q1[r] + c1;
                float mx = fmaxf(l0, l1);
                float x0 = expf(l0 - mx), x1 = expf(l1 - mx);
                float inv = 1.f / (x0 + x1);
                __builtin_nontemporal_store(x0 * inv, &out_y[e * 2 + 0]);
                __builtin_nontemporal_store(x1 * inv, &out_y[e * 2 + 1]);
            }
        }
    }
}

extern "C" void kernel_launch(void* const* d_in, const int* in_sizes, int n_in,
                              void* d_out, int out_size, void* d_ws, size_t ws_size,
                              hipStream_t stream)
{
    const float* x     = (const float*)d_in[0];
    const void*  ei    = d_in[1];
    const float* eattr = (const float*)d_in[2];
    const float* aW0   = (const float*)d_in[3];
    const float* ab0   = (const float*)d_in[4];
    const float* mW0   = (const float*)d_in[5];
    const float* mb0   = (const float*)d_in[6];
    const float* eps0  = (const float*)d_in[7];
    const float* aW1   = (const float*)d_in[8];
    const float* ab1   = (const float*)d_in[9];
    const float* mW1   = (const float*)d_in[10];
    const float* mb1   = (const float*)d_in[11];
    const float* eps1  = (const float*)d_in[12];
    const float* lpW1  = (const float*)d_in[13];
    const float* lpb1  = (const float*)d_in[14];
    const float* lpW2  = (const float*)d_in[15];
    const float* lpb2  = (const float*)d_in[16];

    const int E = in_sizes[1] / 2;
    const long long NTAB = (long long)NNODES * DIM;   // 6.4M

    float* wsf  = (float*)d_ws;
    int*   flag = (int*)d_ws;
    float* agg  = wsf + 64;
    short* wt   = (short*)(agg + NTAB);
    unsigned short* xb_h2b = (unsigned short*)(wt + 196608); // x bf16, later h2 bf16
    unsigned short* h1b    = xb_h2b + NTAB;
    int* counts = (int*)(h1b + NTAB);
    int* cursor = counts + 50048;
    int* perm   = cursor + 50048;
    int* srcs   = perm + E;
    int* dsts   = srcs + E;
    unsigned short* eattrs = (unsigned short*)(dsts + E);  // sorted bf16 eattr

    float* out_he = (float*)d_out;
    float* out_y  = out_he + (long long)E * DIM;

    const short* aW0hi = wt,           *aW0lo = wt + 8192;
    const short* aW1hi = wt + 16384,   *aW1lo = wt + 24576;
    const short* mW0hi = wt + 32768,   *mW0lo = wt + 65536;
    const short* mW1hi = wt + 98304,   *mW1lo = wt + 131072;
    const short* lpW1hi = wt + 163840, *lpW1lo = wt + 180224;

    detect_mode_kernel<<<1, 256, 0, stream>>>(ei, flag);
    prep_weights<<<384, 256, 0, stream>>>(aW0, aW1, mW0, mW1, lpW1, eps0, eps1, wt);
    f32_to_bf16_kernel<<<(int)(NTAB / 8 / 256), 256, 0, stream>>>(x, xb_h2b, NTAB);

    // ---- CSR build (edge structure is layer-invariant) ----
    hipMemsetAsync(counts, 0, 50048 * sizeof(int), stream);
    hist_kernel<<<1024, 256, 0, stream>>>(ei, flag, counts, E);
    scan_kernel<<<1, 1024, 0, stream>>>(counts, cursor);
    scatter_kernel<<<1024, 256, 0, stream>>>(ei, flag, cursor, perm, srcs, dsts, E);
    eattr_sort_bf16<<<(E * DEDGE / 8 + 255) / 256, 256, 0, stream>>>(eattr, perm, eattrs, E);

    const int eblocks = (E + 63) / 64;
    const int nblocks = (NNODES + 63) / 64;

    // ---- layer 0 ----
    hipMemsetAsync(agg, 0, NTAB * sizeof(float), stream);
    edge_msg_sorted<<<eblocks, 256, 0, stream>>>(xb_h2b, eattrs, srcs, dsts,
                                                 aW0hi, aW0lo, ab0, agg, E);
    node_update_mfma<<<nblocks, 256, 0, stream>>>(agg, xb_h2b, mW0hi, mW0lo, mb0, h1b, 0);

    // ---- layer 1 ----
    hipMemsetAsync(agg, 0, NTAB * sizeof(float), stream);
    edge_msg_sorted<<<eblocks, 256, 0, stream>>>(h1b, eattrs, srcs, dsts,
                                                 aW1hi, aW1lo, ab1, agg, E);
    node_update_mfma<<<nblocks, 256, 0, stream>>>(agg, h1b, mW1hi, mW1lo, mb1, xb_h2b, 1);

    // ---- link predictor head ----
    edge_head_mfma<<<eblocks, 256, 0, stream>>>(xb_h2b, ei, flag, lpW1hi, lpW1lo, lpb1, lpW2, lpb2,
                                                out_he, out_y, E);
}

// Round 7
// 660.017 us; speedup vs baseline: 3.0382x; 1.1016x over previous
//
#include <hip/hip_runtime.h>
#include <math.h>

#define NNODES 50000
#define DIM 128
#define DEDGE 64

typedef __attribute__((ext_vector_type(8))) short bf16x8;
typedef __attribute__((ext_vector_type(4))) float f32x4;
typedef __attribute__((ext_vector_type(2))) float f32x2;

__device__ __forceinline__ float bf_lo(unsigned u) { return __builtin_bit_cast(float, u << 16); }
__device__ __forceinline__ float bf_hi(unsigned u) { return __builtin_bit_cast(float, u & 0xFFFF0000u); }
__device__ __forceinline__ float bf_s(short s) {
    return __builtin_bit_cast(float, ((unsigned)(unsigned short)s) << 16);
}
__device__ __forceinline__ unsigned short f2b_rtn(float f) {
    unsigned u = __builtin_bit_cast(unsigned, f);
    u += 0x7FFFu + ((u >> 16) & 1u);
    return (unsigned short)(u >> 16);
}

// ---------------------------------------------------------------------------
// edge_index dtype detection (int64 per reference vs int32 per harness doc)
// ---------------------------------------------------------------------------
__global__ void detect_mode_kernel(const void* __restrict__ ei, int* __restrict__ flag) {
    __shared__ int bad;
    if (threadIdx.x == 0) bad = 0;
    __syncthreads();
    const long long* p = (const long long*)ei;
    int localbad = 0;
    for (int i = threadIdx.x; i < 4096; i += blockDim.x) {
        long long v = p[i];
        if (v < 0 || v >= NNODES) localbad = 1;
    }
    if (localbad) atomicOr(&bad, 1);
    __syncthreads();
    if (threadIdx.x == 0) *flag = bad ? 0 : 1;   // 1 = int64 mode
}

__device__ __forceinline__ int load_idx(const void* ei, long long pos, int mode64) {
    if (mode64) return (int)((const long long*)ei)[pos];
    return ((const int*)ei)[pos];
}

// ---------------------------------------------------------------------------
// prep: weights -> FRAGMENT-ORDER single-bf16 tables; (1+eps) folded exactly
// into the h-half (k>=128) of the GIN weights.
// layout (shorts): aW0@0 aW1@8192 mW0@16384 mW1@49152 lpW1@81920  (98304 total)
// ---------------------------------------------------------------------------
__global__ void prep_weights(const float* __restrict__ aW0, const float* __restrict__ aW1,
                             const float* __restrict__ mW0, const float* __restrict__ mW1,
                             const float* __restrict__ lpW1,
                             const float* __restrict__ eps0p, const float* __restrict__ eps1p,
                             short* __restrict__ wt)
{
    int i = blockIdx.x * 256 + threadIdx.x;   // 0..98303 (384 blocks)
    const float* src; int K, off, f;
    float scale_hi = 1.0f;   // applied to k>=128 rows (GIN h-half)
    if (i < 8192)        { src = aW0;  K = 64;  off = 0;     f = i; }
    else if (i < 16384)  { src = aW1;  K = 64;  off = 8192;  f = i - 8192; }
    else if (i < 49152)  { src = mW0;  K = 256; off = 16384; f = i - 16384;
                           scale_hi = 1.0f + eps0p[0]; }
    else if (i < 81920)  { src = mW1;  K = 256; off = 49152; f = i - 49152;
                           scale_hi = 1.0f + eps1p[0]; }
    else                 { src = lpW1; K = 128; off = 81920; f = i - 81920; }
    const int NKC = K >> 5;
    int j = f & 7, l = (f >> 3) & 63, c = f >> 9;
    int kc = c % NKC, n = c / NKC;
    int col = n * 16 + (l & 15);
    int k = kc * 32 + ((l >> 4) << 3) + j;
    float v = src[k * DIM + col];
    if (k >= 128) v *= scale_hi;
    wt[off + f] = (short)f2b_rtn(v);
}

// f32 -> bf16 table conversion (coalesced, 8 elems/thread)
__global__ void f32_to_bf16_kernel(const float* __restrict__ in,
                                   unsigned short* __restrict__ out, long long n)
{
    long long i = ((long long)blockIdx.x * 256 + threadIdx.x) * 8;
    if (i >= n) return;
    f32x4 a = *(const f32x4*)(in + i);
    f32x4 b = *(const f32x4*)(in + i + 4);
    unsigned short v[8];
#pragma unroll
    for (int t = 0; t < 4; t++) { v[t] = f2b_rtn(a[t]); v[4 + t] = f2b_rtn(b[t]); }
    unsigned p0 = v[0] | ((unsigned)v[1] << 16);
    unsigned p1 = v[2] | ((unsigned)v[3] << 16);
    unsigned p2 = v[4] | ((unsigned)v[5] << 16);
    unsigned p3 = v[6] | ((unsigned)v[7] << 16);
    f32x4 pk = {__builtin_bit_cast(float, p0), __builtin_bit_cast(float, p1),
                __builtin_bit_cast(float, p2), __builtin_bit_cast(float, p3)};
    *(f32x4*)(out + i) = pk;
}

// ---------------------------------------------------------------------------
// CSR build: histogram of dst, exclusive scan, scatter to sorted order
// ---------------------------------------------------------------------------
__global__ void hist_kernel(const void* __restrict__ ei, const int* __restrict__ modep,
                            int* __restrict__ counts, int E)
{
    const int mode64 = *modep;
    for (int e = blockIdx.x * 256 + threadIdx.x; e < E; e += gridDim.x * 256)
        atomicAdd(&counts[load_idx(ei, (long long)E + e, mode64)], 1);
}

__global__ __launch_bounds__(1024) void scan_kernel(const int* __restrict__ counts,
                                                    int* __restrict__ cursor)
{
    __shared__ int part[1024];
    const int t = threadIdx.x;
    const int CH = (NNODES + 1023) / 1024;
    const int lo = t * CH, hi = min(lo + CH, NNODES);
    int s = 0;
    for (int i = lo; i < hi; i++) s += counts[i];
    part[t] = s;
    __syncthreads();
    for (int d = 1; d < 1024; d <<= 1) {
        int v = (t >= d) ? part[t - d] : 0;
        __syncthreads();
        part[t] += v;
        __syncthreads();
    }
    int run = (t == 0) ? 0 : part[t - 1];
    for (int i = lo; i < hi; i++) { cursor[i] = run; run += counts[i]; }
}

__global__ void scatter_kernel(const void* __restrict__ ei, const int* __restrict__ modep,
                               int* __restrict__ cursor, int* __restrict__ perm,
                               int* __restrict__ srcs, int* __restrict__ dsts, int E)
{
    const int mode64 = *modep;
    for (int e = blockIdx.x * 256 + threadIdx.x; e < E; e += gridDim.x * 256) {
        int d = load_idx(ei, (long long)E + e, mode64);
        int s = load_idx(ei, e, mode64);
        int pos = atomicAdd(&cursor[d], 1);
        perm[pos] = e;
        srcs[pos] = s;
        dsts[pos] = d;
    }
}

// ---------------------------------------------------------------------------
// eattr -> bf16, permuted into dst-sorted order (linear reads downstream)
// ---------------------------------------------------------------------------
__global__ void eattr_sort_bf16(const float* __restrict__ eattr, const int* __restrict__ perm,
                                unsigned short* __restrict__ out, int E)
{
    long long i = ((long long)blockIdx.x * 256 + threadIdx.x) * 8;
    if (i >= (long long)E * DEDGE) return;
    long long pos = i >> 6;
    int k = (int)(i & 63);
    long long eid = perm[pos];
    f32x4 a = *(const f32x4*)(eattr + eid * DEDGE + k);
    f32x4 b = *(const f32x4*)(eattr + eid * DEDGE + k + 4);
    unsigned short v[8];
#pragma unroll
    for (int t = 0; t < 4; t++) { v[t] = f2b_rtn(a[t]); v[4 + t] = f2b_rtn(b[t]); }
    unsigned p0 = v[0] | ((unsigned)v[1] << 16);
    unsigned p1 = v[2] | ((unsigned)v[3] << 16);
    unsigned p2 = v[4] | ((unsigned)v[5] << 16);
    unsigned p3 = v[6] | ((unsigned)v[7] << 16);
    f32x4 pk = {__builtin_bit_cast(float, p0), __builtin_bit_cast(float, p1),
                __builtin_bit_cast(float, p2), __builtin_bit_cast(float, p3)};
    __builtin_nontemporal_store(pk, (f32x4*)(out + i));
}

// ---------------------------------------------------------------------------
// edge message + scatter over dst-SORTED edges:
//   agg[dst] += relu(h[src] + eattr@W + b)
// A = sorted bf16 eattr (linear nt 16B frags); B = frag-order bf16 W
// (1 MFMA per frag, 16 total). Unrolled segmented epilogue, scalar atomics.
// ---------------------------------------------------------------------------
__global__ __launch_bounds__(256, 4) void edge_msg_sorted(
    const unsigned short* __restrict__ hb, const unsigned short* __restrict__ eattrs,
    const int* __restrict__ srcs, const int* __restrict__ dsts,
    const short* __restrict__ Wb,
    const float* __restrict__ bvec, float* __restrict__ agg, int E)
{
    __shared__ float e_lds[4][16][132];
    const int lane = threadIdx.x & 63;
    const int w = threadIdx.x >> 6;
    const int lg = lane >> 4, lr = lane & 15;
    const long long p0 = ((long long)blockIdx.x * 4 + w) * 16;
    if (p0 >= E) return;

    const long long pos = (p0 + lr < E) ? (p0 + lr) : (E - 1);
    const int sidx = srcs[pos];
    const int didx = dsts[pos];

    f32x4 acc[8];
#pragma unroll
    for (int n = 0; n < 8; n++) {
        float b = bvec[n * 16 + lr];
        acc[n] = (f32x4){b, b, b, b};
    }
    bf16x8 a[2];
#pragma unroll
    for (int kc = 0; kc < 2; kc++)
        a[kc] = __builtin_nontemporal_load(
            (const bf16x8*)(eattrs + pos * DEDGE + kc * 32 + lg * 8));

#pragma unroll
    for (int n = 0; n < 8; n++) {
#pragma unroll
        for (int kc = 0; kc < 2; kc++) {
            bf16x8 bh = *(const bf16x8*)(Wb + ((n * 2 + kc) * 64 + lane) * 8);
            acc[n] = __builtin_amdgcn_mfma_f32_16x16x32_bf16(a[kc], bh, acc[n], 0, 0, 0);
        }
    }
    // D layout: col = n*16+lr, row = lg*4+r
#pragma unroll
    for (int n = 0; n < 8; n++)
#pragma unroll
        for (int r = 0; r < 4; r++)
            e_lds[w][lg * 4 + r][n * 16 + lr] = acc[n][r];

    if (p0 + 16 <= E) {
        unsigned gu[16];
        int dvs[16];
#pragma unroll
        for (int r = 0; r < 16; r++) {
            int si = __shfl(sidx, r);
            gu[r] = *(const unsigned*)&hb[(long long)si * DIM + 2 * lane];
        }
#pragma unroll
        for (int r = 0; r < 16; r++) dvs[r] = __shfl(didx, r);
        float a0 = 0.f, a1 = 0.f;
#pragma unroll
        for (int r = 0; r < 16; r++) {
            f32x2 ev = *(const f32x2*)&e_lds[w][r][2 * lane];
            float m0 = fmaxf(ev.x + bf_lo(gu[r]), 0.f);
            float m1 = fmaxf(ev.y + bf_hi(gu[r]), 0.f);
            if (r > 0 && dvs[r] != dvs[r - 1]) {
                float* d = &agg[(long long)dvs[r - 1] * DIM + 2 * lane];
                unsafeAtomicAdd(d, a0);
                unsafeAtomicAdd(d + 1, a1);
                a0 = 0.f; a1 = 0.f;
            }
            a0 += m0; a1 += m1;
        }
        float* d = &agg[(long long)dvs[15] * DIM + 2 * lane];
        unsafeAtomicAdd(d, a0);
        unsafeAtomicAdd(d + 1, a1);
    } else {
        float a0 = 0.f, a1 = 0.f;
        int prev = -1;
        for (int r = 0; r < 16; r++) {
            if (p0 + r >= E) break;
            int di = __shfl(didx, r);
            int si = __shfl(sidx, r);
            f32x2 ev = *(const f32x2*)&e_lds[w][r][2 * lane];
            unsigned u = *(const unsigned*)&hb[(long long)si * DIM + 2 * lane];
            float m0 = fmaxf(ev.x + bf_lo(u), 0.f);
            float m1 = fmaxf(ev.y + bf_hi(u), 0.f);
            if (di != prev && prev >= 0) {
                float* d = &agg[(long long)prev * DIM + 2 * lane];
                unsafeAtomicAdd(d, a0);
                unsafeAtomicAdd(d + 1, a1);
                a0 = 0.f; a1 = 0.f;
            }
            a0 += m0; a1 += m1; prev = di;
        }
        if (prev >= 0) {
            float* d = &agg[(long long)prev * DIM + 2 * lane];
            unsafeAtomicAdd(d, a0);
            unsafeAtomicAdd(d + 1, a1);
        }
    }
}

// ---------------------------------------------------------------------------
// GIN update: houtb = bf16(act([agg | (1+eps)*h] @ W + b)); eps pre-folded.
// All single-bf16 operands: agg f32 -> RTN bf16 A, h already bf16. 64 MFMA.
// ---------------------------------------------------------------------------
__global__ __launch_bounds__(256, 4) void node_update_mfma(
    const float* __restrict__ agg, const unsigned short* __restrict__ hb,
    const short* __restrict__ Wb, const float* __restrict__ bvec,
    unsigned short* __restrict__ houtb, int relu_flag)
{
    __shared__ float st[4][16][132];
    const int lane = threadIdx.x & 63;
    const int w = threadIdx.x >> 6;
    const int lg = lane >> 4, lr = lane & 15;
    const int n0 = (blockIdx.x * 4 + w) * 16;
    if (n0 >= NNODES) return;
    const int arow = (n0 + lr < NNODES) ? (n0 + lr) : (NNODES - 1);

    f32x4 acc[8];
#pragma unroll
    for (int n = 0; n < 8; n++) {
        float b = bvec[n * 16 + lr];
        acc[n] = (f32x4){b, b, b, b};
    }
#pragma unroll
    for (int kc = 0; kc < 8; kc++) {
        bf16x8 av;
        if (kc < 4) {
            const int k = kc * 32 + lg * 8;
            f32x4 v0 = *(const f32x4*)(agg + (long long)arow * DIM + k);
            f32x4 v1 = *(const f32x4*)(agg + (long long)arow * DIM + k + 4);
#pragma unroll
            for (int i = 0; i < 4; i++) {
                av[i] = (short)f2b_rtn(v0[i]);
                av[4 + i] = (short)f2b_rtn(v1[i]);
            }
        } else {
            av = *(const bf16x8*)(hb + (long long)arow * DIM + (kc - 4) * 32 + lg * 8);
        }
#pragma unroll
        for (int n = 0; n < 8; n++) {
            bf16x8 bh = *(const bf16x8*)(Wb + ((n * 8 + kc) * 64 + lane) * 8);
            acc[n] = __builtin_amdgcn_mfma_f32_16x16x32_bf16(av, bh, acc[n], 0, 0, 0);
        }
    }
#pragma unroll
    for (int n = 0; n < 8; n++) {
#pragma unroll
        for (int r = 0; r < 4; r++) {
            float z = acc[n][r];
            z = relu_flag ? fmaxf(z, 0.f) : (z > 0.f ? z : 0.2f * z);
            st[w][lg * 4 + r][n * 16 + lr] = z;
        }
    }
    for (int r = 0; r < 16; r++) {
        int row = n0 + r;
        if (row >= NNODES) break;
        f32x2 v = *(const f32x2*)&st[w][r][2 * lane];
        unsigned pk = (unsigned)f2b_rtn(v.x) | ((unsigned)f2b_rtn(v.y) << 16);
        *(unsigned*)&houtb[(long long)row * DIM + 2 * lane] = pk;
    }
}

// ---------------------------------------------------------------------------
// edge head: he = h[src]*h[dst] (exact f32 product of bf16), nt-write f32;
// z = leaky(he@W1+b1) with pure-bf16 MFMA (32 total); yhat = softmax2.
// ---------------------------------------------------------------------------
__global__ __launch_bounds__(256, 6) void edge_head_mfma(
    const unsigned short* __restrict__ hb, const void* __restrict__ ei,
    const int* __restrict__ modep,
    const short* __restrict__ W1b, const float* __restrict__ b1,
    const float* __restrict__ W2, const float* __restrict__ b2,
    float* __restrict__ out_he, float* __restrict__ out_y, int E)
{
    const int mode64 = *modep;
    const int lane = threadIdx.x & 63;
    const int w = threadIdx.x >> 6;
    const int lg = lane >> 4, lr = lane & 15;
    const long long e0 = ((long long)blockIdx.x * 4 + w) * 16;
    if (e0 >= E) return;
    const long long erow = (e0 + lr < E) ? (e0 + lr) : (E - 1);
    int si = load_idx(ei, erow, mode64);
    int di = load_idx(ei, (long long)E + erow, mode64);

    f32x4 acc[8];
#pragma unroll
    for (int n = 0; n < 8; n++) {
        float b = b1[n * 16 + lr];
        acc[n] = (f32x4){b, b, b, b};
    }
    bf16x8 ab[4];
#pragma unroll
    for (int kc = 0; kc < 4; kc++) {
        const int k = kc * 32 + lg * 8;
        bf16x8 hs = *(const bf16x8*)(hb + (long long)si * DIM + k);
        bf16x8 hd = *(const bf16x8*)(hb + (long long)di * DIM + k);
        f32x4 p0, p1;
#pragma unroll
        for (int i = 0; i < 4; i++) {
            p0[i] = bf_s(hs[i]) * bf_s(hd[i]);
            p1[i] = bf_s(hs[4 + i]) * bf_s(hd[4 + i]);
        }
        if (e0 + lr < E) {
            __builtin_nontemporal_store(p0, (f32x4*)(out_he + erow * DIM + k));
            __builtin_nontemporal_store(p1, (f32x4*)(out_he + erow * DIM + k + 4));
        }
#pragma unroll
        for (int i = 0; i < 4; i++) {
            ab[kc][i] = (short)f2b_rtn(p0[i]);
            ab[kc][4 + i] = (short)f2b_rtn(p1[i]);
        }
    }
#pragma unroll
    for (int n = 0; n < 8; n++) {
#pragma unroll
        for (int kc = 0; kc < 4; kc++) {
            bf16x8 bh = *(const bf16x8*)(W1b + ((n * 4 + kc) * 64 + lane) * 8);
            acc[n] = __builtin_amdgcn_mfma_f32_16x16x32_bf16(ab[kc], bh, acc[n], 0, 0, 0);
        }
    }
    float q0[4] = {0.f, 0.f, 0.f, 0.f}, q1[4] = {0.f, 0.f, 0.f, 0.f};
#pragma unroll
    for (int n = 0; n < 8; n++) {
        float w2a = W2[(n * 16 + lr) * 2 + 0];
        float w2b = W2[(n * 16 + lr) * 2 + 1];
#pragma unroll
        for (int r = 0; r < 4; r++) {
            float z = acc[n][r];
            z = z > 0.f ? z : 0.2f * z;
            q0[r] = fmaf(z, w2a, q0[r]);
            q1[r] = fmaf(z, w2b, q1[r]);
        }
    }
#pragma unroll
    for (int m = 1; m < 16; m <<= 1) {
#pragma unroll
        for (int r = 0; r < 4; r++) {
            q0[r] += __shfl_xor(q0[r], m);
            q1[r] += __shfl_xor(q1[r], m);
        }
    }
    if (lr == 0) {
        float c0 = b2[0], c1 = b2[1];
#pragma unroll
        for (int r = 0; r < 4; r++) {
            long long e = e0 + lg * 4 + r;
            if (e < E) {
                float l0 = q0[r] + c0, l1 = q1[r] + c1;
                float mx = fmaxf(l0, l1);
                float x0 = expf(l0 - mx), x1 = expf(l1 - mx);
                float inv = 1.f / (x0 + x1);
                __builtin_nontemporal_store(x0 * inv, &out_y[e * 2 + 0]);
                __builtin_nontemporal_store(x1 * inv, &out_y[e * 2 + 1]);
            }
        }
    }
}

extern "C" void kernel_launch(void* const* d_in, const int* in_sizes, int n_in,
                              void* d_out, int out_size, void* d_ws, size_t ws_size,
                              hipStream_t stream)
{
    const float* x     = (const float*)d_in[0];
    const void*  ei    = d_in[1];
    const float* eattr = (const float*)d_in[2];
    const float* aW0   = (const float*)d_in[3];
    const float* ab0   = (const float*)d_in[4];
    const float* mW0   = (const float*)d_in[5];
    const float* mb0   = (const float*)d_in[6];
    const float* eps0  = (const float*)d_in[7];
    const float* aW1   = (const float*)d_in[8];
    const float* ab1   = (const float*)d_in[9];
    const float* mW1   = (const float*)d_in[10];
    const float* mb1   = (const float*)d_in[11];
    const float* eps1  = (const float*)d_in[12];
    const float* lpW1  = (const float*)d_in[13];
    const float* lpb1  = (const float*)d_in[14];
    const float* lpW2  = (const float*)d_in[15];
    const float* lpb2  = (const float*)d_in[16];

    const int E = in_sizes[1] / 2;
    const long long NTAB = (long long)NNODES * DIM;   // 6.4M

    float* wsf  = (float*)d_ws;
    int*   flag = (int*)d_ws;
    float* agg  = wsf + 64;
    short* wt   = (short*)(agg + NTAB);
    unsigned short* xb_h2b = (unsigned short*)(wt + 98304); // x bf16, later h2 bf16
    unsigned short* h1b    = xb_h2b + NTAB;
    int* counts = (int*)(h1b + NTAB);
    int* cursor = counts + 50048;
    int* perm   = cursor + 50048;
    int* srcs   = perm + E;
    int* dsts   = srcs + E;
    unsigned short* eattrs = (unsigned short*)(dsts + E);  // sorted bf16 eattr

    float* out_he = (float*)d_out;
    float* out_y  = out_he + (long long)E * DIM;

    const short* aW0b  = wt;
    const short* aW1b  = wt + 8192;
    const short* mW0b  = wt + 16384;
    const short* mW1b  = wt + 49152;
    const short* lpW1b = wt + 81920;

    detect_mode_kernel<<<1, 256, 0, stream>>>(ei, flag);
    prep_weights<<<384, 256, 0, stream>>>(aW0, aW1, mW0, mW1, lpW1, eps0, eps1, wt);
    f32_to_bf16_kernel<<<(int)(NTAB / 8 / 256), 256, 0, stream>>>(x, xb_h2b, NTAB);

    // ---- CSR build (edge structure is layer-invariant) ----
    hipMemsetAsync(counts, 0, 50048 * sizeof(int), stream);
    hist_kernel<<<1024, 256, 0, stream>>>(ei, flag, counts, E);
    scan_kernel<<<1, 1024, 0, stream>>>(counts, cursor);
    scatter_kernel<<<1024, 256, 0, stream>>>(ei, flag, cursor, perm, srcs, dsts, E);
    eattr_sort_bf16<<<(E * DEDGE / 8 + 255) / 256, 256, 0, stream>>>(eattr, perm, eattrs, E);

    const int eblocks = (E + 63) / 64;
    const int nblocks = (NNODES + 63) / 64;

    // ---- layer 0 ----
    hipMemsetAsync(agg, 0, NTAB * sizeof(float), stream);
    edge_msg_sorted<<<eblocks, 256, 0, stream>>>(xb_h2b, eattrs, srcs, dsts,
                                                 aW0b, ab0, agg, E);
    node_update_mfma<<<nblocks, 256, 0, stream>>>(agg, xb_h2b, mW0b, mb0, h1b, 0);

    // ---- layer 1 ----
    hipMemsetAsync(agg, 0, NTAB * sizeof(float), stream);
    edge_msg_sorted<<<eblocks, 256, 0, stream>>>(h1b, eattrs, srcs, dsts,
                                                 aW1b, ab1, agg, E);
    node_update_mfma<<<nblocks, 256, 0, stream>>>(agg, h1b, mW1b, mb1, xb_h2b, 1);

    // ---- link predictor head ----
    edge_head_mfma<<<eblocks, 256, 0, stream>>>(xb_h2b, ei, flag, lpW1b, lpb1, lpW2, lpb2,
                                                out_he, out_y, E);
}

// Round 8
// 632.055 us; speedup vs baseline: 3.1727x; 1.0442x over previous
//
#include <hip/hip_runtime.h>
#include <math.h>

#define NNODES 50000
#define DIM 128
#define DEDGE 64

typedef __attribute__((ext_vector_type(8))) short bf16x8;
typedef __attribute__((ext_vector_type(4))) float f32x4;
typedef __attribute__((ext_vector_type(2))) float f32x2;

__device__ __forceinline__ float bf_lo(unsigned u) { return __builtin_bit_cast(float, u << 16); }
__device__ __forceinline__ float bf_hi(unsigned u) { return __builtin_bit_cast(float, u & 0xFFFF0000u); }
__device__ __forceinline__ float bf_s(short s) {
    return __builtin_bit_cast(float, ((unsigned)(unsigned short)s) << 16);
}
__device__ __forceinline__ unsigned short f2b_rtn(float f) {
    unsigned u = __builtin_bit_cast(unsigned, f);
    u += 0x7FFFu + ((u >> 16) & 1u);
    return (unsigned short)(u >> 16);
}

// ---------------------------------------------------------------------------
// edge_index dtype detection (int64 per reference vs int32 per harness doc)
// ---------------------------------------------------------------------------
__global__ void detect_mode_kernel(const void* __restrict__ ei, int* __restrict__ flag) {
    __shared__ int bad;
    if (threadIdx.x == 0) bad = 0;
    __syncthreads();
    const long long* p = (const long long*)ei;
    int localbad = 0;
    for (int i = threadIdx.x; i < 4096; i += blockDim.x) {
        long long v = p[i];
        if (v < 0 || v >= NNODES) localbad = 1;
    }
    if (localbad) atomicOr(&bad, 1);
    __syncthreads();
    if (threadIdx.x == 0) *flag = bad ? 0 : 1;   // 1 = int64 mode
}

__device__ __forceinline__ int load_idx(const void* ei, long long pos, int mode64) {
    if (mode64) return (int)((const long long*)ei)[pos];
    return ((const int*)ei)[pos];
}

// ---------------------------------------------------------------------------
// prep: weights -> FRAGMENT-ORDER single-bf16 tables; (1+eps) folded exactly
// into the h-half (k>=128) of the GIN weights.
// layout (shorts): aW0@0 aW1@8192 mW0@16384 mW1@49152 lpW1@81920  (98304 total)
// ---------------------------------------------------------------------------
__global__ void prep_weights(const float* __restrict__ aW0, const float* __restrict__ aW1,
                             const float* __restrict__ mW0, const float* __restrict__ mW1,
                             const float* __restrict__ lpW1,
                             const float* __restrict__ eps0p, const float* __restrict__ eps1p,
                             short* __restrict__ wt)
{
    int i = blockIdx.x * 256 + threadIdx.x;   // 0..98303 (384 blocks)
    const float* src; int K, off, f;
    float scale_hi = 1.0f;   // applied to k>=128 rows (GIN h-half)
    if (i < 8192)        { src = aW0;  K = 64;  off = 0;     f = i; }
    else if (i < 16384)  { src = aW1;  K = 64;  off = 8192;  f = i - 8192; }
    else if (i < 49152)  { src = mW0;  K = 256; off = 16384; f = i - 16384;
                           scale_hi = 1.0f + eps0p[0]; }
    else if (i < 81920)  { src = mW1;  K = 256; off = 49152; f = i - 49152;
                           scale_hi = 1.0f + eps1p[0]; }
    else                 { src = lpW1; K = 128; off = 81920; f = i - 81920; }
    const int NKC = K >> 5;
    int j = f & 7, l = (f >> 3) & 63, c = f >> 9;
    int kc = c % NKC, n = c / NKC;
    int col = n * 16 + (l & 15);
    int k = kc * 32 + ((l >> 4) << 3) + j;
    float v = src[k * DIM + col];
    if (k >= 128) v *= scale_hi;
    wt[off + f] = (short)f2b_rtn(v);
}

// f32 -> bf16 table conversion (coalesced, 8 elems/thread)
__global__ void f32_to_bf16_kernel(const float* __restrict__ in,
                                   unsigned short* __restrict__ out, long long n)
{
    long long i = ((long long)blockIdx.x * 256 + threadIdx.x) * 8;
    if (i >= n) return;
    f32x4 a = *(const f32x4*)(in + i);
    f32x4 b = *(const f32x4*)(in + i + 4);
    unsigned short v[8];
#pragma unroll
    for (int t = 0; t < 4; t++) { v[t] = f2b_rtn(a[t]); v[4 + t] = f2b_rtn(b[t]); }
    unsigned p0 = v[0] | ((unsigned)v[1] << 16);
    unsigned p1 = v[2] | ((unsigned)v[3] << 16);
    unsigned p2 = v[4] | ((unsigned)v[5] << 16);
    unsigned p3 = v[6] | ((unsigned)v[7] << 16);
    f32x4 pk = {__builtin_bit_cast(float, p0), __builtin_bit_cast(float, p1),
                __builtin_bit_cast(float, p2), __builtin_bit_cast(float, p3)};
    *(f32x4*)(out + i) = pk;
}

// ---------------------------------------------------------------------------
// CSR build: histogram of dst, exclusive scan, scatter to sorted order
// ---------------------------------------------------------------------------
__global__ void hist_kernel(const void* __restrict__ ei, const int* __restrict__ modep,
                            int* __restrict__ counts, int E)
{
    const int mode64 = *modep;
    for (int e = blockIdx.x * 256 + threadIdx.x; e < E; e += gridDim.x * 256)
        atomicAdd(&counts[load_idx(ei, (long long)E + e, mode64)], 1);
}

__global__ __launch_bounds__(1024) void scan_kernel(const int* __restrict__ counts,
                                                    int* __restrict__ cursor)
{
    __shared__ int part[1024];
    const int t = threadIdx.x;
    const int CH = (NNODES + 1023) / 1024;
    const int lo = t * CH, hi = min(lo + CH, NNODES);
    int s = 0;
    for (int i = lo; i < hi; i++) s += counts[i];
    part[t] = s;
    __syncthreads();
    for (int d = 1; d < 1024; d <<= 1) {
        int v = (t >= d) ? part[t - d] : 0;
        __syncthreads();
        part[t] += v;
        __syncthreads();
    }
    int run = (t == 0) ? 0 : part[t - 1];
    for (int i = lo; i < hi; i++) { cursor[i] = run; run += counts[i]; }
}

__global__ void scatter_kernel(const void* __restrict__ ei, const int* __restrict__ modep,
                               int* __restrict__ cursor, int* __restrict__ perm,
                               int* __restrict__ srcs, int* __restrict__ dsts, int E)
{
    const int mode64 = *modep;
    for (int e = blockIdx.x * 256 + threadIdx.x; e < E; e += gridDim.x * 256) {
        int d = load_idx(ei, (long long)E + e, mode64);
        int s = load_idx(ei, e, mode64);
        int pos = atomicAdd(&cursor[d], 1);
        perm[pos] = e;
        srcs[pos] = s;
        dsts[pos] = d;
    }
}

// ---------------------------------------------------------------------------
// eattr -> bf16, permuted into dst-sorted order (linear reads downstream)
// ---------------------------------------------------------------------------
__global__ void eattr_sort_bf16(const float* __restrict__ eattr, const int* __restrict__ perm,
                                unsigned short* __restrict__ out, int E)
{
    long long i = ((long long)blockIdx.x * 256 + threadIdx.x) * 8;
    if (i >= (long long)E * DEDGE) return;
    long long pos = i >> 6;
    int k = (int)(i & 63);
    long long eid = perm[pos];
    f32x4 a = *(const f32x4*)(eattr + eid * DEDGE + k);
    f32x4 b = *(const f32x4*)(eattr + eid * DEDGE + k + 4);
    unsigned short v[8];
#pragma unroll
    for (int t = 0; t < 4; t++) { v[t] = f2b_rtn(a[t]); v[4 + t] = f2b_rtn(b[t]); }
    unsigned p0 = v[0] | ((unsigned)v[1] << 16);
    unsigned p1 = v[2] | ((unsigned)v[3] << 16);
    unsigned p2 = v[4] | ((unsigned)v[5] << 16);
    unsigned p3 = v[6] | ((unsigned)v[7] << 16);
    f32x4 pk = {__builtin_bit_cast(float, p0), __builtin_bit_cast(float, p1),
                __builtin_bit_cast(float, p2), __builtin_bit_cast(float, p3)};
    __builtin_nontemporal_store(pk, (f32x4*)(out + i));
}

// ---------------------------------------------------------------------------
// edge message + scatter over dst-SORTED edges, 2 sub-tiles (32 edges) / wave:
//   agg[dst] += relu(h[src] + eattr@W + b)
// LDS buffer reused across sub-tiles; segmented sum carried across the
// boundary; scalar atomics only at run boundaries.
// ---------------------------------------------------------------------------
__global__ __launch_bounds__(256, 4) void edge_msg_sorted(
    const unsigned short* __restrict__ hb, const unsigned short* __restrict__ eattrs,
    const int* __restrict__ srcs, const int* __restrict__ dsts,
    const short* __restrict__ Wb,
    const float* __restrict__ bvec, float* __restrict__ agg, int E)
{
    __shared__ float e_lds[4][16][132];
    const int lane = threadIdx.x & 63;
    const int w = threadIdx.x >> 6;
    const int lg = lane >> 4, lr = lane & 15;
    const long long p0 = ((long long)blockIdx.x * 4 + w) * 32;
    if (p0 >= E) return;

    float bias0 = bvec[0 * 16 + lr], bias1 = bvec[1 * 16 + lr],
          bias2 = bvec[2 * 16 + lr], bias3 = bvec[3 * 16 + lr],
          bias4 = bvec[4 * 16 + lr], bias5 = bvec[5 * 16 + lr],
          bias6 = bvec[6 * 16 + lr], bias7 = bvec[7 * 16 + lr];
    float bias[8] = {bias0, bias1, bias2, bias3, bias4, bias5, bias6, bias7};

    float a0 = 0.f, a1 = 0.f;
    int prev = -1;

    const bool fullwave = (p0 + 32 <= E);

#pragma unroll
    for (int st = 0; st < 2; st++) {
        const long long t0 = p0 + st * 16;
        if (t0 >= E) break;
        const long long pos = (t0 + lr < E) ? (t0 + lr) : (E - 1);
        const int sidx = srcs[pos];
        const int didx = dsts[pos];

        f32x4 acc[8];
#pragma unroll
        for (int n = 0; n < 8; n++) {
            float b = bias[n];
            acc[n] = (f32x4){b, b, b, b};
        }
        bf16x8 a[2];
#pragma unroll
        for (int kc = 0; kc < 2; kc++)
            a[kc] = __builtin_nontemporal_load(
                (const bf16x8*)(eattrs + pos * DEDGE + kc * 32 + lg * 8));

#pragma unroll
        for (int n = 0; n < 8; n++) {
#pragma unroll
            for (int kc = 0; kc < 2; kc++) {
                bf16x8 bh = *(const bf16x8*)(Wb + ((n * 2 + kc) * 64 + lane) * 8);
                acc[n] = __builtin_amdgcn_mfma_f32_16x16x32_bf16(a[kc], bh, acc[n], 0, 0, 0);
            }
        }
        // D layout: col = n*16+lr, row = lg*4+r
#pragma unroll
        for (int n = 0; n < 8; n++)
#pragma unroll
            for (int r = 0; r < 4; r++)
                e_lds[w][lg * 4 + r][n * 16 + lr] = acc[n][r];

        if (fullwave) {
            unsigned gu[16];
            int dvs[16];
#pragma unroll
            for (int r = 0; r < 16; r++) {
                int si = __shfl(sidx, r);
                gu[r] = *(const unsigned*)&hb[(long long)si * DIM + 2 * lane];
            }
#pragma unroll
            for (int r = 0; r < 16; r++) dvs[r] = __shfl(didx, r);
#pragma unroll
            for (int r = 0; r < 16; r++) {
                f32x2 ev = *(const f32x2*)&e_lds[w][r][2 * lane];
                float m0 = fmaxf(ev.x + bf_lo(gu[r]), 0.f);
                float m1 = fmaxf(ev.y + bf_hi(gu[r]), 0.f);
                if (dvs[r] != prev && prev >= 0) {
                    float* d = &agg[(long long)prev * DIM + 2 * lane];
                    unsafeAtomicAdd(d, a0);
                    unsafeAtomicAdd(d + 1, a1);
                    a0 = 0.f; a1 = 0.f;
                }
                a0 += m0; a1 += m1; prev = dvs[r];
            }
        } else {
            for (int r = 0; r < 16; r++) {
                if (t0 + r >= E) break;
                int di = __shfl(didx, r);
                int si = __shfl(sidx, r);
                f32x2 ev = *(const f32x2*)&e_lds[w][r][2 * lane];
                unsigned u = *(const unsigned*)&hb[(long long)si * DIM + 2 * lane];
                float m0 = fmaxf(ev.x + bf_lo(u), 0.f);
                float m1 = fmaxf(ev.y + bf_hi(u), 0.f);
                if (di != prev && prev >= 0) {
                    float* d = &agg[(long long)prev * DIM + 2 * lane];
                    unsafeAtomicAdd(d, a0);
                    unsafeAtomicAdd(d + 1, a1);
                    a0 = 0.f; a1 = 0.f;
                }
                a0 += m0; a1 += m1; prev = di;
            }
        }
    }
    if (prev >= 0) {
        float* d = &agg[(long long)prev * DIM + 2 * lane];
        unsafeAtomicAdd(d, a0);
        unsafeAtomicAdd(d + 1, a1);
    }
}

// ---------------------------------------------------------------------------
// GIN update: houtb = bf16(act([agg | (1+eps)*h] @ W + b)); eps pre-folded.
// agg streamed non-temporally (one-shot), h already bf16. 64 MFMA.
// ---------------------------------------------------------------------------
__global__ __launch_bounds__(256, 4) void node_update_mfma(
    const float* __restrict__ agg, const unsigned short* __restrict__ hb,
    const short* __restrict__ Wb, const float* __restrict__ bvec,
    unsigned short* __restrict__ houtb, int relu_flag)
{
    __shared__ float st[4][16][132];
    const int lane = threadIdx.x & 63;
    const int w = threadIdx.x >> 6;
    const int lg = lane >> 4, lr = lane & 15;
    const int n0 = (blockIdx.x * 4 + w) * 16;
    if (n0 >= NNODES) return;
    const int arow = (n0 + lr < NNODES) ? (n0 + lr) : (NNODES - 1);

    f32x4 acc[8];
#pragma unroll
    for (int n = 0; n < 8; n++) {
        float b = bvec[n * 16 + lr];
        acc[n] = (f32x4){b, b, b, b};
    }
#pragma unroll
    for (int kc = 0; kc < 8; kc++) {
        bf16x8 av;
        if (kc < 4) {
            const int k = kc * 32 + lg * 8;
            f32x4 v0 = __builtin_nontemporal_load((const f32x4*)(agg + (long long)arow * DIM + k));
            f32x4 v1 = __builtin_nontemporal_load((const f32x4*)(agg + (long long)arow * DIM + k + 4));
#pragma unroll
            for (int i = 0; i < 4; i++) {
                av[i] = (short)f2b_rtn(v0[i]);
                av[4 + i] = (short)f2b_rtn(v1[i]);
            }
        } else {
            av = *(const bf16x8*)(hb + (long long)arow * DIM + (kc - 4) * 32 + lg * 8);
        }
#pragma unroll
        for (int n = 0; n < 8; n++) {
            bf16x8 bh = *(const bf16x8*)(Wb + ((n * 8 + kc) * 64 + lane) * 8);
            acc[n] = __builtin_amdgcn_mfma_f32_16x16x32_bf16(av, bh, acc[n], 0, 0, 0);
        }
    }
#pragma unroll
    for (int n = 0; n < 8; n++) {
#pragma unroll
        for (int r = 0; r < 4; r++) {
            float z = acc[n][r];
            z = relu_flag ? fmaxf(z, 0.f) : (z > 0.f ? z : 0.2f * z);
            st[w][lg * 4 + r][n * 16 + lr] = z;
        }
    }
    for (int r = 0; r < 16; r++) {
        int row = n0 + r;
        if (row >= NNODES) break;
        f32x2 v = *(const f32x2*)&st[w][r][2 * lane];
        unsigned pk = (unsigned)f2b_rtn(v.x) | ((unsigned)f2b_rtn(v.y) << 16);
        *(unsigned*)&houtb[(long long)row * DIM + 2 * lane] = pk;
    }
}

// ---------------------------------------------------------------------------
// edge head: he = h[src]*h[dst] (exact f32 product of bf16), nt-write f32;
// z = leaky(he@W1+b1), 32 MFMA; yhat = softmax2, COALESCED 128B store/tile
// via per-lane export select + cross-group shuffle. E%16==0 fast path.
// ---------------------------------------------------------------------------
__global__ __launch_bounds__(256, 6) void edge_head_mfma(
    const unsigned short* __restrict__ hb, const void* __restrict__ ei,
    const int* __restrict__ modep,
    const short* __restrict__ W1b, const float* __restrict__ b1,
    const float* __restrict__ W2, const float* __restrict__ b2,
    float* __restrict__ out_he, float* __restrict__ out_y, int E)
{
    const int mode64 = *modep;
    const int lane = threadIdx.x & 63;
    const int w = threadIdx.x >> 6;
    const int lg = lane >> 4, lr = lane & 15;
    const long long e0 = ((long long)blockIdx.x * 4 + w) * 16;
    if (e0 >= E) return;
    const bool full = (e0 + 16 <= E);
    const long long erow = (full || e0 + lr < E) ? (e0 + lr) : (E - 1);
    int si = load_idx(ei, erow, mode64);
    int di = load_idx(ei, (long long)E + erow, mode64);

    f32x4 acc[8];
#pragma unroll
    for (int n = 0; n < 8; n++) {
        float b = b1[n * 16 + lr];
        acc[n] = (f32x4){b, b, b, b};
    }
    bf16x8 ab[4];
#pragma unroll
    for (int kc = 0; kc < 4; kc++) {
        const int k = kc * 32 + lg * 8;
        bf16x8 hs = *(const bf16x8*)(hb + (long long)si * DIM + k);
        bf16x8 hd = *(const bf16x8*)(hb + (long long)di * DIM + k);
        f32x4 p0, p1;
#pragma unroll
        for (int i = 0; i < 4; i++) {
            p0[i] = bf_s(hs[i]) * bf_s(hd[i]);
            p1[i] = bf_s(hs[4 + i]) * bf_s(hd[4 + i]);
        }
        if (full || e0 + lr < E) {
            __builtin_nontemporal_store(p0, (f32x4*)(out_he + erow * DIM + k));
            __builtin_nontemporal_store(p1, (f32x4*)(out_he + erow * DIM + k + 4));
        }
#pragma unroll
        for (int i = 0; i < 4; i++) {
            ab[kc][i] = (short)f2b_rtn(p0[i]);
            ab[kc][4 + i] = (short)f2b_rtn(p1[i]);
        }
    }
#pragma unroll
    for (int n = 0; n < 8; n++) {
#pragma unroll
        for (int kc = 0; kc < 4; kc++) {
            bf16x8 bh = *(const bf16x8*)(W1b + ((n * 4 + kc) * 64 + lane) * 8);
            acc[n] = __builtin_amdgcn_mfma_f32_16x16x32_bf16(ab[kc], bh, acc[n], 0, 0, 0);
        }
    }
    float q0[4] = {0.f, 0.f, 0.f, 0.f}, q1[4] = {0.f, 0.f, 0.f, 0.f};
#pragma unroll
    for (int n = 0; n < 8; n++) {
        float w2a = W2[(n * 16 + lr) * 2 + 0];
        float w2b = W2[(n * 16 + lr) * 2 + 1];
#pragma unroll
        for (int r = 0; r < 4; r++) {
            float z = acc[n][r];
            z = z > 0.f ? z : 0.2f * z;
            q0[r] = fmaf(z, w2a, q0[r]);
            q1[r] = fmaf(z, w2b, q1[r]);
        }
    }
#pragma unroll
    for (int m = 1; m < 16; m <<= 1) {
#pragma unroll
        for (int r = 0; r < 4; r++) {
            q0[r] += __shfl_xor(q0[r], m);
            q1[r] += __shfl_xor(q1[r], m);
        }
    }
    // softmax per edge: edge = e0 + lg*4 + r; all lanes in a 16-group hold q
    float c0 = b2[0], c1 = b2[1];
    float s0[4], s1[4];
#pragma unroll
    for (int r = 0; r < 4; r++) {
        float l0 = q0[r] + c0, l1 = q1[r] + c1;
        float mx = fmaxf(l0, l1);
        float x0 = expf(l0 - mx), x1 = expf(l1 - mx);
        float inv = 1.f / (x0 + x1);
        s0[r] = x0 * inv;
        s1[r] = x1 * inv;
    }
    if (full) {
        // export: lane L provides s_{L&1}[(L>>1)&3]; static select tree
        float ea = (lane & 2) ? s0[1] : s0[0];
        float eb = (lane & 2) ? s0[3] : s0[2];
        float ec = (lane & 2) ? s1[1] : s1[0];
        float ed = (lane & 2) ? s1[3] : s1[2];
        float e0v = (lane & 4) ? eb : ea;
        float e1v = (lane & 4) ? ed : ec;
        float ex = (lane & 1) ? e1v : e0v;
        float v = __shfl(ex, ((lane >> 3) << 4) + (lane & 7));
        if (lane < 32)
            __builtin_nontemporal_store(v, &out_y[e0 * 2 + lane]);
    } else if (lr == 0) {
#pragma unroll
        for (int r = 0; r < 4; r++) {
            long long e = e0 + lg * 4 + r;
            if (e < E) {
                out_y[e * 2 + 0] = s0[r];
                out_y[e * 2 + 1] = s1[r];
            }
        }
    }
}

extern "C" void kernel_launch(void* const* d_in, const int* in_sizes, int n_in,
                              void* d_out, int out_size, void* d_ws, size_t ws_size,
                              hipStream_t stream)
{
    const float* x     = (const float*)d_in[0];
    const void*  ei    = d_in[1];
    const float* eattr = (const float*)d_in[2];
    const float* aW0   = (const float*)d_in[3];
    const float* ab0   = (const float*)d_in[4];
    const float* mW0   = (const float*)d_in[5];
    const float* mb0   = (const float*)d_in[6];
    const float* eps0  = (const float*)d_in[7];
    const float* aW1   = (const float*)d_in[8];
    const float* ab1   = (const float*)d_in[9];
    const float* mW1   = (const float*)d_in[10];
    const float* mb1   = (const float*)d_in[11];
    const float* eps1  = (const float*)d_in[12];
    const float* lpW1  = (const float*)d_in[13];
    const float* lpb1  = (const float*)d_in[14];
    const float* lpW2  = (const float*)d_in[15];
    const float* lpb2  = (const float*)d_in[16];

    const int E = in_sizes[1] / 2;
    const long long NTAB = (long long)NNODES * DIM;   // 6.4M

    float* wsf  = (float*)d_ws;
    int*   flag = (int*)d_ws;
    float* agg  = wsf + 64;
    short* wt   = (short*)(agg + NTAB);
    unsigned short* xb_h2b = (unsigned short*)(wt + 98304); // x bf16, later h2 bf16
    unsigned short* h1b    = xb_h2b + NTAB;
    int* counts = (int*)(h1b + NTAB);
    int* cursor = counts + 50048;
    int* perm   = cursor + 50048;
    int* srcs   = perm + E;
    int* dsts   = srcs + E;
    unsigned short* eattrs = (unsigned short*)(dsts + E);  // sorted bf16 eattr

    float* out_he = (float*)d_out;
    float* out_y  = out_he + (long long)E * DIM;

    const short* aW0b  = wt;
    const short* aW1b  = wt + 8192;
    const short* mW0b  = wt + 16384;
    const short* mW1b  = wt + 49152;
    const short* lpW1b = wt + 81920;

    detect_mode_kernel<<<1, 256, 0, stream>>>(ei, flag);
    prep_weights<<<384, 256, 0, stream>>>(aW0, aW1, mW0, mW1, lpW1, eps0, eps1, wt);
    f32_to_bf16_kernel<<<(int)(NTAB / 8 / 256), 256, 0, stream>>>(x, xb_h2b, NTAB);

    // ---- CSR build (edge structure is layer-invariant) ----
    hipMemsetAsync(counts, 0, 50048 * sizeof(int), stream);
    hist_kernel<<<1024, 256, 0, stream>>>(ei, flag, counts, E);
    scan_kernel<<<1, 1024, 0, stream>>>(counts, cursor);
    scatter_kernel<<<1024, 256, 0, stream>>>(ei, flag, cursor, perm, srcs, dsts, E);
    eattr_sort_bf16<<<(E * DEDGE / 8 + 255) / 256, 256, 0, stream>>>(eattr, perm, eattrs, E);

    const int eblocks32 = (E + 127) / 128;   // 32 edges per wave, 4 waves/block
    const int eblocks16 = (E + 63) / 64;     // 16 edges per wave
    const int nblocks = (NNODES + 63) / 64;

    // ---- layer 0 ----
    hipMemsetAsync(agg, 0, NTAB * sizeof(float), stream);
    edge_msg_sorted<<<eblocks32, 256, 0, stream>>>(xb_h2b, eattrs, srcs, dsts,
                                                   aW0b, ab0, agg, E);
    node_update_mfma<<<nblocks, 256, 0, stream>>>(agg, xb_h2b, mW0b, mb0, h1b, 0);

    // ---- layer 1 ----
    hipMemsetAsync(agg, 0, NTAB * sizeof(float), stream);
    edge_msg_sorted<<<eblocks32, 256, 0, stream>>>(h1b, eattrs, srcs, dsts,
                                                   aW1b, ab1, agg, E);
    node_update_mfma<<<nblocks, 256, 0, stream>>>(agg, h1b, mW1b, mb1, xb_h2b, 1);

    // ---- link predictor head ----
    edge_head_mfma<<<eblocks16, 256, 0, stream>>>(xb_h2b, ei, flag, lpW1b, lpb1, lpW2, lpb2,
                                                  out_he, out_y, E);
}